// Round 8
// baseline (394.930 us; speedup 1.0000x reference)
//
#include <hip/hip_runtime.h>
#include <hip/hip_fp16.h>
#include <cstddef>
#include <cstdint>

#define C 128

typedef short bf16x8 __attribute__((ext_vector_type(8)));
typedef float f32x4 __attribute__((ext_vector_type(4)));

__device__ __forceinline__ unsigned f2bf_hi(float f) {
  unsigned u = __float_as_uint(f);
  return (u + 0x7fffu + ((u >> 16) & 1u)) >> 16;
}

// ---- W prep: W[j][k][c] fp32 -> fragment-ordered bf16 hi/lo planes ----
// 12 planes (j*4 + half*2 + ch), each 8192 shorts (64 cols x 128 k).
// Within plane: off = kc*2048 + ct*512 + (g*16 + l15)*8 + i
//   where c = ch*64 + ct*16 + l15, k = kc*32 + g*8 + i.
// Batch b (0..47): plane = b>>2, kc = b&3 -> contiguous 2048 shorts at b*2048.
__global__ __launch_bounds__(256) void prep_w(
    const float* __restrict__ W, unsigned short* __restrict__ wf) {
  const int idx = blockIdx.x * 256 + threadIdx.x;  // 0..49151
  const int j = idx >> 14, k = (idx >> 7) & 127, c = idx & 127;
  const float v = W[idx];
  const unsigned hb = f2bf_hi(v);
  const unsigned lb = f2bf_hi(v - __uint_as_float(hb << 16));
  const int ch = c >> 6, cc = c & 63, ct = cc >> 4, l15 = cc & 15;
  const int kc = k >> 5, kk = k & 31, g = kk >> 3, i = kk & 7;
  const int off = kc * 2048 + ct * 512 + (g * 16 + l15) * 8 + i;
  wf[(size_t)(j * 4 + 0 + ch) * 8192 + off] = (unsigned short)hb;  // hi plane
  wf[(size_t)(j * 4 + 2 + ch) * 8192 + off] = (unsigned short)lb;  // lo plane
}

// ---- x prep: fp32 [N][128] -> bf16 hi/lo [NP][128] (zero-padded) ------
__global__ __launch_bounds__(256) void prep_x(
    const float* __restrict__ x, unsigned short* __restrict__ xh,
    unsigned short* __restrict__ xl, int N, int NP) {
  const int idx = blockIdx.x * 256 + threadIdx.x;
  if (idx >= NP * C) return;
  const float v = (idx < N * C) ? x[idx] : 0.0f;
  const unsigned hb = f2bf_hi(v);
  const unsigned lb = f2bf_hi(v - __uint_as_float(hb << 16));
  xh[idx] = (unsigned short)hb;
  xl[idx] = (unsigned short)lb;
}

// ---- fused 3x linear via MFMA split-bf16, no LDS, no barriers ---------
// block 256 (4 waves) = 64 rows; wave = 16 rows x 128 cols, A stationary.
// 48 batches; batch b: 4 coalesced 1KB B-frag loads + 4-8 MFMAs.
__global__ __launch_bounds__(256) void gemm3_mfma(
    const unsigned short* __restrict__ xh, const unsigned short* __restrict__ xl,
    const unsigned short* __restrict__ wf, const float* __restrict__ bias,
    float* __restrict__ out, __half* __restrict__ h1, __half* __restrict__ h2,
    int N) {
  const int row0 = blockIdx.x * 64;
  const int tid = threadIdx.x;
  const int lane = tid & 63, wid = tid >> 6;
  const int l15 = lane & 15, g = lane >> 4;

  // A fragments (loaded once, stationary for all 48 batches)
  const size_t arow = (size_t)(row0 + wid * 16 + l15) * C;
  bf16x8 ah[4], al[4];
#pragma unroll
  for (int kc = 0; kc < 4; ++kc) {
    ah[kc] = *reinterpret_cast<const bf16x8*>(xh + arow + kc * 32 + g * 8);
    al[kc] = *reinterpret_cast<const bf16x8*>(xl + arow + kc * 32 + g * 8);
  }

  f32x4 acc[8];
#pragma unroll
  for (int ct = 0; ct < 8; ++ct) acc[ct] = (f32x4){0.f, 0.f, 0.f, 0.f};

  bf16x8 frag[3][4];  // 3-slot rolling prefetch, distance 2

#define FB(slot, b)                                                          \
  {                                                                          \
    _Pragma("unroll") for (int ct = 0; ct < 4; ++ct)                         \
        frag[slot][ct] = *reinterpret_cast<const bf16x8*>(                   \
            wf + (size_t)(b) * 2048 + ct * 512 + lane * 8);                  \
  }

  FB(0, 0);
  FB(1, 1);

#pragma unroll
  for (int b = 0; b < 48; ++b) {
    if (b + 2 < 48) FB((b + 2) % 3, b + 2);
    const int kc = b & 3;
    const int ch = (b >> 2) & 1;
    const bool use_lo = ((b >> 3) & 1) == 0;  // planes 0,1 of each j = hi half
#pragma unroll
    for (int ct = 0; ct < 4; ++ct) {
      const int ctg = ch * 4 + ct;
      const bf16x8 bfr = frag[b % 3][ct];
      acc[ctg] = __builtin_amdgcn_mfma_f32_16x16x32_bf16(ah[kc], bfr, acc[ctg], 0, 0, 0);
      if (use_lo)
        acc[ctg] = __builtin_amdgcn_mfma_f32_16x16x32_bf16(al[kc], bfr, acc[ctg], 0, 0, 0);
    }
    // epilogue at j boundaries (b = 15, 31, 47)
    if ((b & 15) == 15) {
      const int j = b >> 4;
      if (j == 0) {
#pragma unroll
        for (int ct = 0; ct < 8; ++ct) {
          const int col = ct * 16 + l15;
          const float bv = bias[col];
#pragma unroll
          for (int q = 0; q < 4; ++q) {
            const int gr = row0 + wid * 16 + g * 4 + q;
            if (gr < N) out[(size_t)gr * 384 + col] = acc[ct][q] + bv;
          }
        }
      } else {
        __half* const hp = (j == 1) ? h1 : h2;
#pragma unroll
        for (int ct = 0; ct < 8; ++ct) {
          const int col = ct * 16 + l15;
          const float bv = bias[j * C + col];
#pragma unroll
          for (int q = 0; q < 4; ++q) {
            const int gr = row0 + wid * 16 + g * 4 + q;
            if (gr < N) hp[(size_t)gr * C + col] = __float2half(acc[ct][q] + bv);
          }
        }
      }
      if (j < 2) {
#pragma unroll
        for (int ct = 0; ct < 8; ++ct) acc[ct] = (f32x4){0.f, 0.f, 0.f, 0.f};
      }
    }
  }
#undef FB
}

// ---- CSR build --------------------------------------------------------
__global__ __launch_bounds__(256) void hist_rows(
    const int* __restrict__ row, int* __restrict__ cnt, int E) {
  int i = blockIdx.x * 256 + threadIdx.x;
  int stride = gridDim.x * 256;
  for (; i < E; i += stride) atomicAdd(&cnt[row[i]], 1);
}

__global__ __launch_bounds__(1024) void scan_local(
    const int* __restrict__ cnt, int* __restrict__ part,
    int* __restrict__ bsum, int N) {
  __shared__ int wsum[16];
  const int tid = threadIdx.x;
  const int i = blockIdx.x * 1024 + tid;
  const int v = (i < N) ? cnt[i] : 0;
  const int lane = tid & 63, w = tid >> 6;
  int s = v;
#pragma unroll
  for (int off = 1; off < 64; off <<= 1) {
    int t = __shfl_up(s, off, 64);
    if (lane >= off) s += t;
  }
  if (lane == 63) wsum[w] = s;
  __syncthreads();
  if (tid < 16) {
    int ws = wsum[tid];
#pragma unroll
    for (int off = 1; off < 16; off <<= 1) {
      int t = __shfl_up(ws, off, 16);
      if (tid >= off) ws += t;
    }
    wsum[tid] = ws;
  }
  __syncthreads();
  const int woff = w ? wsum[w - 1] : 0;
  if (i < N) part[i] = woff + s - v;
  if (tid == 0) bsum[blockIdx.x] = wsum[15];
}

__global__ __launch_bounds__(64) void scan_carry(
    const int* __restrict__ bsum, int* __restrict__ carry,
    int* __restrict__ row_ptr, int nb, int N) {
  const int tid = threadIdx.x;
  const int v = (tid < nb) ? bsum[tid] : 0;
  int s = v;
#pragma unroll
  for (int off = 1; off < 64; off <<= 1) {
    int t = __shfl_up(s, off, 64);
    if (tid >= off) s += t;
  }
  if (tid < nb) carry[tid] = s - v;
  if (tid == 63) row_ptr[N] = s;
}

__global__ __launch_bounds__(1024) void scan_apply(
    int* __restrict__ part, const int* __restrict__ carry,
    int* __restrict__ cursor, int N) {
  const int i = blockIdx.x * 1024 + threadIdx.x;
  if (i < N) {
    const int v = part[i] + carry[blockIdx.x];
    part[i] = v;
    cursor[i] = v;
  }
}

__global__ __launch_bounds__(256) void scatter_edges(
    const int* __restrict__ row, const int* __restrict__ col,
    const float* __restrict__ val, int* __restrict__ cursor,
    int2* __restrict__ ep, int E) {
  int i = blockIdx.x * 256 + threadIdx.x;
  int stride = gridDim.x * 256;
  for (; i < E; i += stride) {
    int r = row[i];
    int pos = atomicAdd(&cursor[r], 1);
    ep[pos] = make_int2(col[i], __float_as_int(val[i]));
  }
}

// ---- SpMM merged: out[:,128:256] = A h1 ; t = A h2 (fp16 gathers) -----
__global__ __launch_bounds__(256) void spmm12(
    const __half* __restrict__ h1t, const __half* __restrict__ h2t,
    const int* __restrict__ rp, const int2* __restrict__ ep,
    float* __restrict__ out, __half* __restrict__ t, int N) {
  const int r = blockIdx.x * 4 + (threadIdx.x >> 6);
  if (r >= N) return;
  const int c2 = (threadIdx.x & 63) << 1;
  const int s = rp[r], e = rp[r + 1];
  float2 p0 = make_float2(0.f, 0.f), p1 = p0, q0 = p0, q1 = p0;
  int i = s;
  for (; i + 1 < e; i += 2) {
    const int2 e0 = ep[i], e1 = ep[i + 1];
    const float v0 = __int_as_float(e0.y), v1 = __int_as_float(e1.y);
    const float2 a0 = __half22float2(*reinterpret_cast<const __half2*>(h1t + (size_t)e0.x * C + c2));
    const float2 b0 = __half22float2(*reinterpret_cast<const __half2*>(h2t + (size_t)e0.x * C + c2));
    const float2 a1 = __half22float2(*reinterpret_cast<const __half2*>(h1t + (size_t)e1.x * C + c2));
    const float2 b1 = __half22float2(*reinterpret_cast<const __half2*>(h2t + (size_t)e1.x * C + c2));
    p0.x += v0 * a0.x; p0.y += v0 * a0.y;
    q0.x += v0 * b0.x; q0.y += v0 * b0.y;
    p1.x += v1 * a1.x; p1.y += v1 * a1.y;
    q1.x += v1 * b1.x; q1.y += v1 * b1.y;
  }
  if (i < e) {
    const int2 e0 = ep[i];
    const float v0 = __int_as_float(e0.y);
    const float2 a0 = __half22float2(*reinterpret_cast<const __half2*>(h1t + (size_t)e0.x * C + c2));
    const float2 b0 = __half22float2(*reinterpret_cast<const __half2*>(h2t + (size_t)e0.x * C + c2));
    p0.x += v0 * a0.x; p0.y += v0 * a0.y;
    q0.x += v0 * b0.x; q0.y += v0 * b0.y;
  }
  float2 rp1 = make_float2(p0.x + p1.x, p0.y + p1.y);
  float2 rq = make_float2(q0.x + q1.x, q0.y + q1.y);
  *reinterpret_cast<float2*>(out + (size_t)r * 384 + C + c2) = rp1;
  *reinterpret_cast<__half2*>(t + (size_t)r * C + c2) = __float22half2_rn(rq);
}

// ---- SpMM: fp16 gather -> fp32 out column slice -----------------------
__global__ __launch_bounds__(256) void spmm_h2f(
    const __half* __restrict__ h, const int* __restrict__ rp,
    const int2* __restrict__ ep, float* __restrict__ outp, int N, int ostride) {
  const int r = blockIdx.x * 4 + (threadIdx.x >> 6);
  if (r >= N) return;
  const int c2 = (threadIdx.x & 63) << 1;
  const int s = rp[r], e = rp[r + 1];
  float2 a0 = make_float2(0.f, 0.f), a1 = a0, a2 = a0, a3 = a0;
  int i = s;
  for (; i + 3 < e; i += 4) {
    const int2 e0 = ep[i], e1 = ep[i + 1], e2 = ep[i + 2], e3 = ep[i + 3];
    const float2 g0 = __half22float2(*reinterpret_cast<const __half2*>(h + (size_t)e0.x * C + c2));
    const float2 g1 = __half22float2(*reinterpret_cast<const __half2*>(h + (size_t)e1.x * C + c2));
    const float2 g2 = __half22float2(*reinterpret_cast<const __half2*>(h + (size_t)e2.x * C + c2));
    const float2 g3 = __half22float2(*reinterpret_cast<const __half2*>(h + (size_t)e3.x * C + c2));
    const float v0 = __int_as_float(e0.y), v1 = __int_as_float(e1.y);
    const float v2 = __int_as_float(e2.y), v3 = __int_as_float(e3.y);
    a0.x += v0 * g0.x; a0.y += v0 * g0.y;
    a1.x += v1 * g1.x; a1.y += v1 * g1.y;
    a2.x += v2 * g2.x; a2.y += v2 * g2.y;
    a3.x += v3 * g3.x; a3.y += v3 * g3.y;
  }
  for (; i < e; ++i) {
    const int2 e0 = ep[i];
    const float v0 = __int_as_float(e0.y);
    const float2 g0 = __half22float2(*reinterpret_cast<const __half2*>(h + (size_t)e0.x * C + c2));
    a0.x += v0 * g0.x; a0.y += v0 * g0.y;
  }
  float2 res = make_float2((a0.x + a1.x) + (a2.x + a3.x),
                           (a0.y + a1.y) + (a2.y + a3.y));
  *reinterpret_cast<float2*>(outp + (size_t)r * ostride + c2) = res;
}

// ---- SpMM: fp16 gather -> fp16 table (fallback path) ------------------
__global__ __launch_bounds__(256) void spmm_h2h(
    const __half* __restrict__ h, const int* __restrict__ rp,
    const int2* __restrict__ ep, __half* __restrict__ outp, int N) {
  const int r = blockIdx.x * 4 + (threadIdx.x >> 6);
  if (r >= N) return;
  const int c2 = (threadIdx.x & 63) << 1;
  const int s = rp[r], e = rp[r + 1];
  float2 a0 = make_float2(0.f, 0.f), a1 = a0;
  int i = s;
  for (; i + 1 < e; i += 2) {
    const int2 e0 = ep[i], e1 = ep[i + 1];
    const float2 g0 = __half22float2(*reinterpret_cast<const __half2*>(h + (size_t)e0.x * C + c2));
    const float2 g1 = __half22float2(*reinterpret_cast<const __half2*>(h + (size_t)e1.x * C + c2));
    const float v0 = __int_as_float(e0.y), v1 = __int_as_float(e1.y);
    a0.x += v0 * g0.x; a0.y += v0 * g0.y;
    a1.x += v1 * g1.x; a1.y += v1 * g1.y;
  }
  if (i < e) {
    const int2 e0 = ep[i];
    const float v0 = __int_as_float(e0.y);
    const float2 g0 = __half22float2(*reinterpret_cast<const __half2*>(h + (size_t)e0.x * C + c2));
    a0.x += v0 * g0.x; a0.y += v0 * g0.y;
  }
  float2 res = make_float2(a0.x + a1.x, a0.y + a1.y);
  *reinterpret_cast<__half2*>(outp + (size_t)r * C + c2) = __float22half2_rn(res);
}

extern "C" void kernel_launch(void* const* d_in, const int* in_sizes, int n_in,
                              void* d_out, int out_size, void* d_ws, size_t ws_size,
                              hipStream_t stream) {
  const float* x  = (const float*)d_in[0];
  const float* W  = (const float*)d_in[1];
  const float* b  = (const float*)d_in[2];
  const float* ev = (const float*)d_in[3];
  const int*   er = (const int*)d_in[4];
  const int*   ec = (const int*)d_in[5];
  const int N = in_sizes[0] / C;
  const int E = in_sizes[3];
  float* out = (float*)d_out;

  const int NP = ((N + 63) / 64) * 64;
  char* base = (char*)d_ws;
  size_t off = 0;
  auto alloc = [&](size_t bytes) {
    char* p = base + off;
    off += (bytes + 255) & ~(size_t)255;
    return p;
  };
  __half* h1 = (__half*)alloc((size_t)N * C * 2);
  __half* h2 = (__half*)alloc((size_t)N * C * 2);
  unsigned short* xh = (unsigned short*)alloc((size_t)NP * C * 2);
  unsigned short* xl = (unsigned short*)alloc((size_t)NP * C * 2);
  unsigned short* wf = (unsigned short*)alloc((size_t)12 * 8192 * 2);
  int* row_ptr = (int*)alloc((size_t)(N + 1) * 4);
  int* cursor  = (int*)alloc((size_t)N * 4);
  int* bsum    = (int*)alloc(64 * 4);
  int* carry   = (int*)alloc(64 * 4);
  int2* ep     = (int2*)alloc((size_t)E * 8);
  const size_t need_t = off + (size_t)N * C * 2;
  __half* t;
  bool merged;
  if (ws_size >= need_t) { t = (__half*)alloc((size_t)N * C * 2); merged = true; }
  else                   { t = h1; merged = false; }  // h1 dead after pass-1

  const int nb = (N + 1023) / 1024;

  // prep (weights + split x)
  prep_w<<<192, 256, 0, stream>>>(W, wf);
  prep_x<<<(NP * C + 255) / 256, 256, 0, stream>>>(x, xh, xl, N, NP);

  // CSR build (cursor doubles as count buffer)
  hipMemsetAsync(cursor, 0, (size_t)N * sizeof(int), stream);
  const int eb0 = (E + 255) / 256;
  const int eblocks = eb0 < 2048 ? eb0 : 2048;
  hist_rows<<<eblocks, 256, 0, stream>>>(er, cursor, E);
  scan_local<<<nb, 1024, 0, stream>>>(cursor, row_ptr, bsum, N);
  scan_carry<<<1, 64, 0, stream>>>(bsum, carry, row_ptr, nb, N);
  scan_apply<<<nb, 1024, 0, stream>>>(row_ptr, carry, cursor, N);
  scatter_edges<<<eblocks, 256, 0, stream>>>(er, ec, ev, cursor, ep, E);

  // fused linears (MFMA, no LDS, register-pipelined B frags)
  gemm3_mfma<<<NP / 64, 256, 0, stream>>>(xh, xl, wf, b, out, h1, h2, N);

  // SpMM passes
  const int sblocks = (N + 3) / 4;
  if (merged) {
    spmm12<<<sblocks, 256, 0, stream>>>(h1, h2, row_ptr, ep, out, t, N);
  } else {
    spmm_h2f<<<sblocks, 256, 0, stream>>>(h1, row_ptr, ep, out + C, N, 3 * C);
    spmm_h2h<<<sblocks, 256, 0, stream>>>(h2, row_ptr, ep, t, N);
  }
  spmm_h2f<<<sblocks, 256, 0, stream>>>(t, row_ptr, ep, out + 2 * C, N, 3 * C);
}

// Round 9
// 213.635 us; speedup vs baseline: 1.8486x; 1.8486x over previous
//
#include <hip/hip_runtime.h>
#include <hip/hip_fp16.h>
#include <cstddef>
#include <cstdint>

#define C 128

typedef short bf16x8 __attribute__((ext_vector_type(8)));
typedef float f32x4 __attribute__((ext_vector_type(4)));

__device__ __forceinline__ unsigned f2bf_hi(float f) {
  unsigned u = __float_as_uint(f);
  return (u + 0x7fffu + ((u >> 16) & 1u)) >> 16;
}

// ---- W prep: W[j][k][c] fp32 -> fragment-ordered bf16 hi/lo planes ----
// 12 planes (j*4 + half*2 + ch), each 8192 shorts (64 cols x 128 k).
// Within plane: off = kc*2048 + ct*512 + (g*16 + l15)*8 + i
//   where c = ch*64 + ct*16 + l15, k = kc*32 + g*8 + i.   (verified R8)
__global__ __launch_bounds__(256) void prep_w(
    const float* __restrict__ W, unsigned short* __restrict__ wf) {
  const int idx = blockIdx.x * 256 + threadIdx.x;  // 0..49151
  const int j = idx >> 14, k = (idx >> 7) & 127, c = idx & 127;
  const float v = W[idx];
  const unsigned hb = f2bf_hi(v);
  const unsigned lb = f2bf_hi(v - __uint_as_float(hb << 16));
  const int ch = c >> 6, cc = c & 63, ct = cc >> 4, l15 = cc & 15;
  const int kc = k >> 5, kk = k & 31, g = kk >> 3, i = kk & 7;
  const int off = kc * 2048 + ct * 512 + (g * 16 + l15) * 8 + i;
  wf[(size_t)(j * 4 + 0 + ch) * 8192 + off] = (unsigned short)hb;  // hi plane
  wf[(size_t)(j * 4 + 2 + ch) * 8192 + off] = (unsigned short)lb;  // lo plane
}

// ---- x prep: fp32 [N][128] -> bf16 hi/lo [NP][128] (zero-padded) ------
__global__ __launch_bounds__(256) void prep_x(
    const float* __restrict__ x, unsigned short* __restrict__ xh,
    unsigned short* __restrict__ xl, int N, int NP) {
  const int idx = blockIdx.x * 256 + threadIdx.x;
  if (idx >= NP * C) return;
  const float v = (idx < N * C) ? x[idx] : 0.0f;
  const unsigned hb = f2bf_hi(v);
  const unsigned lb = f2bf_hi(v - __uint_as_float(hb << 16));
  xh[idx] = (unsigned short)hb;
  xl[idx] = (unsigned short)lb;
}

// ---- fused 3x linear: W-stationary in VGPRs, stream x rows ------------
// 1D grid, bid -> (chunk, v): chunk = (bid%8) + 8*(bid/48), v = (bid%48)>>3.
// v = j*2 + ch. Same-chunk variants share bid%8 -> same XCD (L2 x-reuse).
// Block = 4 waves; each wave streams 8 16-row tiles (block = 512 rows).
// Per wave: B-frags (64 cols x K=128, hi+lo) = 32 frags = 128 VGPRs, once.
__global__ __launch_bounds__(256, 2) void gemm3_ws(
    const unsigned short* __restrict__ xh, const unsigned short* __restrict__ xl,
    const unsigned short* __restrict__ wf, const float* __restrict__ bias,
    float* __restrict__ out, __half* __restrict__ h1, __half* __restrict__ h2,
    int N) {
  const int bid = blockIdx.x;
  const int q48 = bid / 48, r48 = bid % 48;
  const int chunk = (r48 & 7) + 8 * q48;
  const int v = r48 >> 3;  // 0..5
  const int j = v >> 1, ch = v & 1;
  const int tid = threadIdx.x;
  const int lane = tid & 63, wid = tid >> 6;
  const int l15 = lane & 15, g = lane >> 4;

  // stationary B fragments
  const unsigned short* ph = wf + (size_t)(j * 4 + 0 + ch) * 8192 + lane * 8;
  const unsigned short* pl = wf + (size_t)(j * 4 + 2 + ch) * 8192 + lane * 8;
  bf16x8 bh[4][4], bl[4][4];
#pragma unroll
  for (int kc = 0; kc < 4; ++kc)
#pragma unroll
    for (int ct = 0; ct < 4; ++ct) {
      bh[kc][ct] = *reinterpret_cast<const bf16x8*>(ph + kc * 2048 + ct * 512);
      bl[kc][ct] = *reinterpret_cast<const bf16x8*>(pl + kc * 2048 + ct * 512);
    }

  float bv[4];
#pragma unroll
  for (int ct = 0; ct < 4; ++ct) bv[ct] = bias[j * C + ch * 64 + ct * 16 + l15];

  const int t0 = chunk * 32 + wid;  // global 16-row tile, step 4 per wave

  bf16x8 a0h[4], a0l[4], a1h[4], a1l[4];

#define LOADA(AH, AL, T)                                                    \
  {                                                                         \
    const size_t ar = (size_t)((T)*16 + l15) * C + g * 8;                   \
    _Pragma("unroll") for (int kc = 0; kc < 4; ++kc) {                      \
      AH[kc] = *reinterpret_cast<const bf16x8*>(xh + ar + kc * 32);         \
      AL[kc] = *reinterpret_cast<const bf16x8*>(xl + ar + kc * 32);         \
    }                                                                       \
  }

#define COMPSTORE(AH, AL, T)                                                \
  {                                                                         \
    f32x4 acc[4];                                                           \
    _Pragma("unroll") for (int ct = 0; ct < 4; ++ct)                        \
        acc[ct] = (f32x4){0.f, 0.f, 0.f, 0.f};                              \
    _Pragma("unroll") for (int kc = 0; kc < 4; ++kc)                        \
        _Pragma("unroll") for (int ct = 0; ct < 4; ++ct) {                  \
      acc[ct] = __builtin_amdgcn_mfma_f32_16x16x32_bf16(AH[kc], bh[kc][ct], \
                                                        acc[ct], 0, 0, 0);  \
      acc[ct] = __builtin_amdgcn_mfma_f32_16x16x32_bf16(AL[kc], bh[kc][ct], \
                                                        acc[ct], 0, 0, 0);  \
      acc[ct] = __builtin_amdgcn_mfma_f32_16x16x32_bf16(AH[kc], bl[kc][ct], \
                                                        acc[ct], 0, 0, 0);  \
    }                                                                       \
    const int grb = (T)*16 + g * 4;                                         \
    if (j == 0) {                                                           \
      _Pragma("unroll") for (int ct = 0; ct < 4; ++ct) {                    \
        const int col = ch * 64 + ct * 16 + l15;                            \
        _Pragma("unroll") for (int qq = 0; qq < 4; ++qq) {                  \
          const int gr = grb + qq;                                          \
          if (gr < N) out[(size_t)gr * 384 + col] = acc[ct][qq] + bv[ct];   \
        }                                                                   \
      }                                                                     \
    } else {                                                                \
      __half* const hp = (j == 1) ? h1 : h2;                                \
      _Pragma("unroll") for (int ct = 0; ct < 4; ++ct) {                    \
        const int col = ch * 64 + ct * 16 + l15;                            \
        _Pragma("unroll") for (int qq = 0; qq < 4; ++qq) {                  \
          const int gr = grb + qq;                                          \
          if (gr < N)                                                       \
            hp[(size_t)gr * C + col] = __float2half(acc[ct][qq] + bv[ct]);  \
        }                                                                   \
      }                                                                     \
    }                                                                       \
  }

  LOADA(a0h, a0l, t0);
#pragma unroll
  for (int ti = 0; ti < 8; ti += 2) {
    LOADA(a1h, a1l, t0 + (ti + 1) * 4);
    COMPSTORE(a0h, a0l, t0 + ti * 4);
    if (ti + 2 < 8) LOADA(a0h, a0l, t0 + (ti + 2) * 4);
    COMPSTORE(a1h, a1l, t0 + (ti + 1) * 4);
  }
#undef LOADA
#undef COMPSTORE
}

// ---- CSR build --------------------------------------------------------
__global__ __launch_bounds__(256) void hist_rows(
    const int* __restrict__ row, int* __restrict__ cnt, int E) {
  int i = blockIdx.x * 256 + threadIdx.x;
  int stride = gridDim.x * 256;
  for (; i < E; i += stride) atomicAdd(&cnt[row[i]], 1);
}

__global__ __launch_bounds__(1024) void scan_local(
    const int* __restrict__ cnt, int* __restrict__ part,
    int* __restrict__ bsum, int N) {
  __shared__ int wsum[16];
  const int tid = threadIdx.x;
  const int i = blockIdx.x * 1024 + tid;
  const int v = (i < N) ? cnt[i] : 0;
  const int lane = tid & 63, w = tid >> 6;
  int s = v;
#pragma unroll
  for (int off = 1; off < 64; off <<= 1) {
    int t = __shfl_up(s, off, 64);
    if (lane >= off) s += t;
  }
  if (lane == 63) wsum[w] = s;
  __syncthreads();
  if (tid < 16) {
    int ws = wsum[tid];
#pragma unroll
    for (int off = 1; off < 16; off <<= 1) {
      int t = __shfl_up(ws, off, 16);
      if (tid >= off) ws += t;
    }
    wsum[tid] = ws;
  }
  __syncthreads();
  const int woff = w ? wsum[w - 1] : 0;
  if (i < N) part[i] = woff + s - v;
  if (tid == 0) bsum[blockIdx.x] = wsum[15];
}

__global__ __launch_bounds__(64) void scan_carry(
    const int* __restrict__ bsum, int* __restrict__ carry,
    int* __restrict__ row_ptr, int nb, int N) {
  const int tid = threadIdx.x;
  const int v = (tid < nb) ? bsum[tid] : 0;
  int s = v;
#pragma unroll
  for (int off = 1; off < 64; off <<= 1) {
    int t = __shfl_up(s, off, 64);
    if (tid >= off) s += t;
  }
  if (tid < nb) carry[tid] = s - v;
  if (tid == 63) row_ptr[N] = s;
}

__global__ __launch_bounds__(1024) void scan_apply(
    int* __restrict__ part, const int* __restrict__ carry,
    int* __restrict__ cursor, int N) {
  const int i = blockIdx.x * 1024 + threadIdx.x;
  if (i < N) {
    const int v = part[i] + carry[blockIdx.x];
    part[i] = v;
    cursor[i] = v;
  }
}

__global__ __launch_bounds__(256) void scatter_edges(
    const int* __restrict__ row, const int* __restrict__ col,
    const float* __restrict__ val, int* __restrict__ cursor,
    int2* __restrict__ ep, int E) {
  int i = blockIdx.x * 256 + threadIdx.x;
  int stride = gridDim.x * 256;
  for (; i < E; i += stride) {
    int r = row[i];
    int pos = atomicAdd(&cursor[r], 1);
    ep[pos] = make_int2(col[i], __float_as_int(val[i]));
  }
}

// ---- SpMM merged: out[:,128:256] = A h1 ; t = A h2 (fp16 gathers) -----
__global__ __launch_bounds__(256) void spmm12(
    const __half* __restrict__ h1t, const __half* __restrict__ h2t,
    const int* __restrict__ rp, const int2* __restrict__ ep,
    float* __restrict__ out, __half* __restrict__ t, int N) {
  const int r = blockIdx.x * 4 + (threadIdx.x >> 6);
  if (r >= N) return;
  const int c2 = (threadIdx.x & 63) << 1;
  const int s = rp[r], e = rp[r + 1];
  float2 p0 = make_float2(0.f, 0.f), p1 = p0, q0 = p0, q1 = p0;
  int i = s;
  for (; i + 1 < e; i += 2) {
    const int2 e0 = ep[i], e1 = ep[i + 1];
    const float v0 = __int_as_float(e0.y), v1 = __int_as_float(e1.y);
    const float2 a0 = __half22float2(*reinterpret_cast<const __half2*>(h1t + (size_t)e0.x * C + c2));
    const float2 b0 = __half22float2(*reinterpret_cast<const __half2*>(h2t + (size_t)e0.x * C + c2));
    const float2 a1 = __half22float2(*reinterpret_cast<const __half2*>(h1t + (size_t)e1.x * C + c2));
    const float2 b1 = __half22float2(*reinterpret_cast<const __half2*>(h2t + (size_t)e1.x * C + c2));
    p0.x += v0 * a0.x; p0.y += v0 * a0.y;
    q0.x += v0 * b0.x; q0.y += v0 * b0.y;
    p1.x += v1 * a1.x; p1.y += v1 * a1.y;
    q1.x += v1 * b1.x; q1.y += v1 * b1.y;
  }
  if (i < e) {
    const int2 e0 = ep[i];
    const float v0 = __int_as_float(e0.y);
    const float2 a0 = __half22float2(*reinterpret_cast<const __half2*>(h1t + (size_t)e0.x * C + c2));
    const float2 b0 = __half22float2(*reinterpret_cast<const __half2*>(h2t + (size_t)e0.x * C + c2));
    p0.x += v0 * a0.x; p0.y += v0 * a0.y;
    q0.x += v0 * b0.x; q0.y += v0 * b0.y;
  }
  float2 rp1 = make_float2(p0.x + p1.x, p0.y + p1.y);
  float2 rq = make_float2(q0.x + q1.x, q0.y + q1.y);
  *reinterpret_cast<float2*>(out + (size_t)r * 384 + C + c2) = rp1;
  *reinterpret_cast<__half2*>(t + (size_t)r * C + c2) = __float22half2_rn(rq);
}

// ---- SpMM: fp16 gather -> fp32 out column slice -----------------------
__global__ __launch_bounds__(256) void spmm_h2f(
    const __half* __restrict__ h, const int* __restrict__ rp,
    const int2* __restrict__ ep, float* __restrict__ outp, int N, int ostride) {
  const int r = blockIdx.x * 4 + (threadIdx.x >> 6);
  if (r >= N) return;
  const int c2 = (threadIdx.x & 63) << 1;
  const int s = rp[r], e = rp[r + 1];
  float2 a0 = make_float2(0.f, 0.f), a1 = a0, a2 = a0, a3 = a0;
  int i = s;
  for (; i + 3 < e; i += 4) {
    const int2 e0 = ep[i], e1 = ep[i + 1], e2 = ep[i + 2], e3 = ep[i + 3];
    const float2 g0 = __half22float2(*reinterpret_cast<const __half2*>(h + (size_t)e0.x * C + c2));
    const float2 g1 = __half22float2(*reinterpret_cast<const __half2*>(h + (size_t)e1.x * C + c2));
    const float2 g2 = __half22float2(*reinterpret_cast<const __half2*>(h + (size_t)e2.x * C + c2));
    const float2 g3 = __half22float2(*reinterpret_cast<const __half2*>(h + (size_t)e3.x * C + c2));
    const float v0 = __int_as_float(e0.y), v1 = __int_as_float(e1.y);
    const float v2 = __int_as_float(e2.y), v3 = __int_as_float(e3.y);
    a0.x += v0 * g0.x; a0.y += v0 * g0.y;
    a1.x += v1 * g1.x; a1.y += v1 * g1.y;
    a2.x += v2 * g2.x; a2.y += v2 * g2.y;
    a3.x += v3 * g3.x; a3.y += v3 * g3.y;
  }
  for (; i < e; ++i) {
    const int2 e0 = ep[i];
    const float v0 = __int_as_float(e0.y);
    const float2 g0 = __half22float2(*reinterpret_cast<const __half2*>(h + (size_t)e0.x * C + c2));
    a0.x += v0 * g0.x; a0.y += v0 * g0.y;
  }
  float2 res = make_float2((a0.x + a1.x) + (a2.x + a3.x),
                           (a0.y + a1.y) + (a2.y + a3.y));
  *reinterpret_cast<float2*>(outp + (size_t)r * ostride + c2) = res;
}

// ---- SpMM: fp16 gather -> fp16 table (fallback path) ------------------
__global__ __launch_bounds__(256) void spmm_h2h(
    const __half* __restrict__ h, const int* __restrict__ rp,
    const int2* __restrict__ ep, __half* __restrict__ outp, int N) {
  const int r = blockIdx.x * 4 + (threadIdx.x >> 6);
  if (r >= N) return;
  const int c2 = (threadIdx.x & 63) << 1;
  const int s = rp[r], e = rp[r + 1];
  float2 a0 = make_float2(0.f, 0.f), a1 = a0;
  int i = s;
  for (; i + 1 < e; i += 2) {
    const int2 e0 = ep[i], e1 = ep[i + 1];
    const float2 g0 = __half22float2(*reinterpret_cast<const __half2*>(h + (size_t)e0.x * C + c2));
    const float2 g1 = __half22float2(*reinterpret_cast<const __half2*>(h + (size_t)e1.x * C + c2));
    const float v0 = __int_as_float(e0.y), v1 = __int_as_float(e1.y);
    a0.x += v0 * g0.x; a0.y += v0 * g0.y;
    a1.x += v1 * g1.x; a1.y += v1 * g1.y;
  }
  if (i < e) {
    const int2 e0 = ep[i];
    const float v0 = __int_as_float(e0.y);
    const float2 g0 = __half22float2(*reinterpret_cast<const __half2*>(h + (size_t)e0.x * C + c2));
    a0.x += v0 * g0.x; a0.y += v0 * g0.y;
  }
  float2 res = make_float2(a0.x + a1.x, a0.y + a1.y);
  *reinterpret_cast<__half2*>(outp + (size_t)r * C + c2) = __float22half2_rn(res);
}

extern "C" void kernel_launch(void* const* d_in, const int* in_sizes, int n_in,
                              void* d_out, int out_size, void* d_ws, size_t ws_size,
                              hipStream_t stream) {
  const float* x  = (const float*)d_in[0];
  const float* W  = (const float*)d_in[1];
  const float* b  = (const float*)d_in[2];
  const float* ev = (const float*)d_in[3];
  const int*   er = (const int*)d_in[4];
  const int*   ec = (const int*)d_in[5];
  const int N = in_sizes[0] / C;
  const int E = in_sizes[3];
  float* out = (float*)d_out;

  // rows padded to 4096 (512 rows/chunk x 8 chunks per XCD-group)
  const int NP3 = ((N + 4095) / 4096) * 4096;
  const int nchunk = NP3 / 512;

  char* base = (char*)d_ws;
  size_t off = 0;
  auto alloc = [&](size_t bytes) {
    char* p = base + off;
    off += (bytes + 255) & ~(size_t)255;
    return p;
  };
  __half* h1 = (__half*)alloc((size_t)N * C * 2);
  __half* h2 = (__half*)alloc((size_t)N * C * 2);
  unsigned short* xh = (unsigned short*)alloc((size_t)NP3 * C * 2);
  unsigned short* xl = (unsigned short*)alloc((size_t)NP3 * C * 2);
  unsigned short* wf = (unsigned short*)alloc((size_t)12 * 8192 * 2);
  int* row_ptr = (int*)alloc((size_t)(N + 1) * 4);
  int* cursor  = (int*)alloc((size_t)N * 4);
  int* bsum    = (int*)alloc(64 * 4);
  int* carry   = (int*)alloc(64 * 4);
  int2* ep     = (int2*)alloc((size_t)E * 8);
  const size_t need_t = off + (size_t)N * C * 2;
  __half* t;
  bool merged;
  if (ws_size >= need_t) { t = (__half*)alloc((size_t)N * C * 2); merged = true; }
  else                   { t = h1; merged = false; }  // h1 dead after pass-1

  const int nb = (N + 1023) / 1024;

  // prep (weights + split x)
  prep_w<<<192, 256, 0, stream>>>(W, wf);
  prep_x<<<(NP3 * C + 255) / 256, 256, 0, stream>>>(x, xh, xl, N, NP3);

  // CSR build (cursor doubles as count buffer)
  hipMemsetAsync(cursor, 0, (size_t)N * sizeof(int), stream);
  const int eb0 = (E + 255) / 256;
  const int eblocks = eb0 < 2048 ? eb0 : 2048;
  hist_rows<<<eblocks, 256, 0, stream>>>(er, cursor, E);
  scan_local<<<nb, 1024, 0, stream>>>(cursor, row_ptr, bsum, N);
  scan_carry<<<1, 64, 0, stream>>>(bsum, carry, row_ptr, nb, N);
  scan_apply<<<nb, 1024, 0, stream>>>(row_ptr, carry, cursor, N);
  scatter_edges<<<eblocks, 256, 0, stream>>>(er, ec, ev, cursor, ep, E);

  // fused linears (MFMA, W-stationary in VGPRs)
  gemm3_ws<<<6 * nchunk, 256, 0, stream>>>(xh, xl, wf, b, out, h1, h2, N);

  // SpMM passes
  const int sblocks = (N + 3) / 4;
  if (merged) {
    spmm12<<<sblocks, 256, 0, stream>>>(h1, h2, row_ptr, ep, out, t, N);
  } else {
    spmm_h2f<<<sblocks, 256, 0, stream>>>(h1, row_ptr, ep, out + C, N, 3 * C);
    spmm_h2h<<<sblocks, 256, 0, stream>>>(h2, row_ptr, ep, t, N);
  }
  spmm_h2f<<<sblocks, 256, 0, stream>>>(t, row_ptr, ep, out + 2 * C, N, 3 * C);
}

// Round 10
// 206.175 us; speedup vs baseline: 1.9155x; 1.0362x over previous
//
#include <hip/hip_runtime.h>
#include <hip/hip_fp16.h>
#include <cstddef>
#include <cstdint>

#define C 128

typedef short bf16x8 __attribute__((ext_vector_type(8)));
typedef float f32x4 __attribute__((ext_vector_type(4)));

__device__ __forceinline__ unsigned f2bf_hi(float f) {
  unsigned u = __float_as_uint(f);
  return (u + 0x7fffu + ((u >> 16) & 1u)) >> 16;
}

// ---- W prep: W[j][k][c] fp32 -> fragment-ordered bf16 hi/lo planes ----
// 12 planes (j*4 + half*2 + ch), each 8192 shorts (64 cols x 128 k).
// Within plane: off = kc*2048 + ct*512 + (g*16 + l15)*8 + i   (verified R8)
__global__ __launch_bounds__(256) void prep_w(
    const float* __restrict__ W, unsigned short* __restrict__ wf) {
  const int idx = blockIdx.x * 256 + threadIdx.x;  // 0..49151
  const int j = idx >> 14, k = (idx >> 7) & 127, c = idx & 127;
  const float v = W[idx];
  const unsigned hb = f2bf_hi(v);
  const unsigned lb = f2bf_hi(v - __uint_as_float(hb << 16));
  const int ch = c >> 6, cc = c & 63, ct = cc >> 4, l15 = cc & 15;
  const int kc = k >> 5, kk = k & 31, g = kk >> 3, i = kk & 7;
  const int off = kc * 2048 + ct * 512 + (g * 16 + l15) * 8 + i;
  wf[(size_t)(j * 4 + 0 + ch) * 8192 + off] = (unsigned short)hb;  // hi plane
  wf[(size_t)(j * 4 + 2 + ch) * 8192 + off] = (unsigned short)lb;  // lo plane
}

// ---- x prep: fp32 [N][128] -> bf16 hi/lo [NP][128] (zero-padded) ------
__global__ __launch_bounds__(256) void prep_x(
    const float* __restrict__ x, unsigned short* __restrict__ xh,
    unsigned short* __restrict__ xl, int N, int NP) {
  const int idx = blockIdx.x * 256 + threadIdx.x;
  if (idx >= NP * C) return;
  const float v = (idx < N * C) ? x[idx] : 0.0f;
  const unsigned hb = f2bf_hi(v);
  const unsigned lb = f2bf_hi(v - __uint_as_float(hb << 16));
  xh[idx] = (unsigned short)hb;
  xl[idx] = (unsigned short)lb;
}

// ---- fused 3x linear: W-stationary in VGPRs, stream x rows ------------
// bid -> (chunk, v): chunk = (bid%8) + 8*(bid/48), v = (bid%48)>>3 = j*2+ch.
// h1/h2 outputs interleaved into h12 [N][256]: j==1 at +0, j==2 at +128.
__global__ __launch_bounds__(256, 2) void gemm3_ws(
    const unsigned short* __restrict__ xh, const unsigned short* __restrict__ xl,
    const unsigned short* __restrict__ wf, const float* __restrict__ bias,
    float* __restrict__ out, __half* __restrict__ h12, int N) {
  const int bid = blockIdx.x;
  const int q48 = bid / 48, r48 = bid % 48;
  const int chunk = (r48 & 7) + 8 * q48;
  const int v = r48 >> 3;  // 0..5
  const int j = v >> 1, ch = v & 1;
  const int tid = threadIdx.x;
  const int lane = tid & 63, wid = tid >> 6;
  const int l15 = lane & 15, g = lane >> 4;

  // stationary B fragments (128 VGPRs)
  const unsigned short* ph = wf + (size_t)(j * 4 + 0 + ch) * 8192 + lane * 8;
  const unsigned short* pl = wf + (size_t)(j * 4 + 2 + ch) * 8192 + lane * 8;
  bf16x8 bh[4][4], bl[4][4];
#pragma unroll
  for (int kc = 0; kc < 4; ++kc)
#pragma unroll
    for (int ct = 0; ct < 4; ++ct) {
      bh[kc][ct] = *reinterpret_cast<const bf16x8*>(ph + kc * 2048 + ct * 512);
      bl[kc][ct] = *reinterpret_cast<const bf16x8*>(pl + kc * 2048 + ct * 512);
    }

  float bv[4];
#pragma unroll
  for (int ct = 0; ct < 4; ++ct) bv[ct] = bias[j * C + ch * 64 + ct * 16 + l15];

  const int t0 = chunk * 32 + wid;  // 16-row tile id, step 4 per wave

  bf16x8 a0h[4], a0l[4], a1h[4], a1l[4];

#define LOADA(AH, AL, T)                                                    \
  {                                                                         \
    const size_t ar = (size_t)((T)*16 + l15) * C + g * 8;                   \
    _Pragma("unroll") for (int kc = 0; kc < 4; ++kc) {                      \
      AH[kc] = *reinterpret_cast<const bf16x8*>(xh + ar + kc * 32);         \
      AL[kc] = *reinterpret_cast<const bf16x8*>(xl + ar + kc * 32);         \
    }                                                                       \
  }

#define COMPSTORE(AH, AL, T)                                                \
  {                                                                         \
    f32x4 acc[4];                                                           \
    _Pragma("unroll") for (int ct = 0; ct < 4; ++ct)                        \
        acc[ct] = (f32x4){0.f, 0.f, 0.f, 0.f};                              \
    _Pragma("unroll") for (int kc = 0; kc < 4; ++kc)                        \
        _Pragma("unroll") for (int ct = 0; ct < 4; ++ct) {                  \
      acc[ct] = __builtin_amdgcn_mfma_f32_16x16x32_bf16(AH[kc], bh[kc][ct], \
                                                        acc[ct], 0, 0, 0);  \
      acc[ct] = __builtin_amdgcn_mfma_f32_16x16x32_bf16(AL[kc], bh[kc][ct], \
                                                        acc[ct], 0, 0, 0);  \
      acc[ct] = __builtin_amdgcn_mfma_f32_16x16x32_bf16(AH[kc], bl[kc][ct], \
                                                        acc[ct], 0, 0, 0);  \
    }                                                                       \
    const int grb = (T)*16 + g * 4;                                         \
    if (j == 0) {                                                           \
      _Pragma("unroll") for (int ct = 0; ct < 4; ++ct) {                    \
        const int col = ch * 64 + ct * 16 + l15;                            \
        _Pragma("unroll") for (int qq = 0; qq < 4; ++qq) {                  \
          const int gr = grb + qq;                                          \
          if (gr < N) out[(size_t)gr * 384 + col] = acc[ct][qq] + bv[ct];   \
        }                                                                   \
      }                                                                     \
    } else {                                                                \
      __half* const hp = h12 + ((j == 2) ? 128 : 0);                        \
      _Pragma("unroll") for (int ct = 0; ct < 4; ++ct) {                    \
        const int col = ch * 64 + ct * 16 + l15;                            \
        _Pragma("unroll") for (int qq = 0; qq < 4; ++qq) {                  \
          const int gr = grb + qq;                                          \
          if (gr < N)                                                       \
            hp[(size_t)gr * 256 + col] = __float2half(acc[ct][qq] + bv[ct]);\
        }                                                                   \
      }                                                                     \
    }                                                                       \
  }

  LOADA(a0h, a0l, t0);
#pragma unroll
  for (int ti = 0; ti < 8; ti += 2) {
    LOADA(a1h, a1l, t0 + (ti + 1) * 4);
    COMPSTORE(a0h, a0l, t0 + ti * 4);
    if (ti + 2 < 8) LOADA(a0h, a0l, t0 + (ti + 2) * 4);
    COMPSTORE(a1h, a1l, t0 + (ti + 1) * 4);
  }
#undef LOADA
#undef COMPSTORE
}

// ---- CSR build --------------------------------------------------------
__global__ __launch_bounds__(256) void hist_rows(
    const int* __restrict__ row, int* __restrict__ cnt, int E) {
  int i = blockIdx.x * 256 + threadIdx.x;
  int stride = gridDim.x * 256;
  for (; i < E; i += stride) atomicAdd(&cnt[row[i]], 1);
}

__global__ __launch_bounds__(1024) void scan_local(
    const int* __restrict__ cnt, int* __restrict__ part,
    int* __restrict__ bsum, int N) {
  __shared__ int wsum[16];
  const int tid = threadIdx.x;
  const int i = blockIdx.x * 1024 + tid;
  const int v = (i < N) ? cnt[i] : 0;
  const int lane = tid & 63, w = tid >> 6;
  int s = v;
#pragma unroll
  for (int off = 1; off < 64; off <<= 1) {
    int t = __shfl_up(s, off, 64);
    if (lane >= off) s += t;
  }
  if (lane == 63) wsum[w] = s;
  __syncthreads();
  if (tid < 16) {
    int ws = wsum[tid];
#pragma unroll
    for (int off = 1; off < 16; off <<= 1) {
      int t = __shfl_up(ws, off, 16);
      if (tid >= off) ws += t;
    }
    wsum[tid] = ws;
  }
  __syncthreads();
  const int woff = w ? wsum[w - 1] : 0;
  if (i < N) part[i] = woff + s - v;
  if (tid == 0) bsum[blockIdx.x] = wsum[15];
}

__global__ __launch_bounds__(64) void scan_carry(
    const int* __restrict__ bsum, int* __restrict__ carry,
    int* __restrict__ row_ptr, int nb, int N) {
  const int tid = threadIdx.x;
  const int v = (tid < nb) ? bsum[tid] : 0;
  int s = v;
#pragma unroll
  for (int off = 1; off < 64; off <<= 1) {
    int t = __shfl_up(s, off, 64);
    if (tid >= off) s += t;
  }
  if (tid < nb) carry[tid] = s - v;
  if (tid == 63) row_ptr[N] = s;
}

__global__ __launch_bounds__(1024) void scan_apply(
    int* __restrict__ part, const int* __restrict__ carry,
    int* __restrict__ cursor, int N) {
  const int i = blockIdx.x * 1024 + threadIdx.x;
  if (i < N) {
    const int v = part[i] + carry[blockIdx.x];
    part[i] = v;
    cursor[i] = v;
  }
}

__global__ __launch_bounds__(256) void scatter_edges(
    const int* __restrict__ row, const int* __restrict__ col,
    const float* __restrict__ val, int* __restrict__ cursor,
    int2* __restrict__ ep, int E) {
  int i = blockIdx.x * 256 + threadIdx.x;
  int stride = gridDim.x * 256;
  for (; i < E; i += stride) {
    int r = row[i];
    int pos = atomicAdd(&cursor[r], 1);
    ep[pos] = make_int2(col[i], __float_as_int(val[i]));
  }
}

// ---- SpMM merged: out[:,128:256] = A h1 ; t = A h2 --------------------
// h12 interleaved [N][256]; 4-edge unroll -> 8 gathers in flight.
__global__ __launch_bounds__(256) void spmm12(
    const __half* __restrict__ h12, const int* __restrict__ rp,
    const int2* __restrict__ ep, float* __restrict__ out,
    __half* __restrict__ t, int tstride, int N) {
  const int r = blockIdx.x * 4 + (threadIdx.x >> 6);
  if (r >= N) return;
  const int c2 = (threadIdx.x & 63) << 1;
  const int s = rp[r], e = rp[r + 1];
  float2 p0 = make_float2(0.f, 0.f), p1 = p0, p2 = p0, p3 = p0;
  float2 q0 = p0, q1 = p0, q2 = p0, q3 = p0;
  int i = s;
  for (; i + 3 < e; i += 4) {
    const int2 e0 = ep[i], e1 = ep[i + 1], e2 = ep[i + 2], e3 = ep[i + 3];
    const size_t b0 = (size_t)e0.x * 256 + c2;
    const size_t b1 = (size_t)e1.x * 256 + c2;
    const size_t b2 = (size_t)e2.x * 256 + c2;
    const size_t b3 = (size_t)e3.x * 256 + c2;
    const float2 a0 = __half22float2(*reinterpret_cast<const __half2*>(h12 + b0));
    const float2 g0 = __half22float2(*reinterpret_cast<const __half2*>(h12 + b0 + 128));
    const float2 a1 = __half22float2(*reinterpret_cast<const __half2*>(h12 + b1));
    const float2 g1 = __half22float2(*reinterpret_cast<const __half2*>(h12 + b1 + 128));
    const float2 a2 = __half22float2(*reinterpret_cast<const __half2*>(h12 + b2));
    const float2 g2 = __half22float2(*reinterpret_cast<const __half2*>(h12 + b2 + 128));
    const float2 a3 = __half22float2(*reinterpret_cast<const __half2*>(h12 + b3));
    const float2 g3 = __half22float2(*reinterpret_cast<const __half2*>(h12 + b3 + 128));
    const float v0 = __int_as_float(e0.y), v1 = __int_as_float(e1.y);
    const float v2 = __int_as_float(e2.y), v3 = __int_as_float(e3.y);
    p0.x += v0 * a0.x; p0.y += v0 * a0.y; q0.x += v0 * g0.x; q0.y += v0 * g0.y;
    p1.x += v1 * a1.x; p1.y += v1 * a1.y; q1.x += v1 * g1.x; q1.y += v1 * g1.y;
    p2.x += v2 * a2.x; p2.y += v2 * a2.y; q2.x += v2 * g2.x; q2.y += v2 * g2.y;
    p3.x += v3 * a3.x; p3.y += v3 * a3.y; q3.x += v3 * g3.x; q3.y += v3 * g3.y;
  }
  for (; i < e; ++i) {
    const int2 e0 = ep[i];
    const size_t b0 = (size_t)e0.x * 256 + c2;
    const float v0 = __int_as_float(e0.y);
    const float2 a0 = __half22float2(*reinterpret_cast<const __half2*>(h12 + b0));
    const float2 g0 = __half22float2(*reinterpret_cast<const __half2*>(h12 + b0 + 128));
    p0.x += v0 * a0.x; p0.y += v0 * a0.y;
    q0.x += v0 * g0.x; q0.y += v0 * g0.y;
  }
  float2 rp1 = make_float2((p0.x + p1.x) + (p2.x + p3.x),
                           (p0.y + p1.y) + (p2.y + p3.y));
  float2 rq = make_float2((q0.x + q1.x) + (q2.x + q3.x),
                          (q0.y + q1.y) + (q2.y + q3.y));
  *reinterpret_cast<float2*>(out + (size_t)r * 384 + C + c2) = rp1;
  *reinterpret_cast<__half2*>(t + (size_t)r * tstride + c2) = __float22half2_rn(rq);
}

// ---- SpMM: fp16 gather (stride hstride) -> fp32 out slice -------------
__global__ __launch_bounds__(256) void spmm_h2f(
    const __half* __restrict__ h, int hstride, const int* __restrict__ rp,
    const int2* __restrict__ ep, float* __restrict__ outp, int N, int ostride) {
  const int r = blockIdx.x * 4 + (threadIdx.x >> 6);
  if (r >= N) return;
  const int c2 = (threadIdx.x & 63) << 1;
  const int s = rp[r], e = rp[r + 1];
  float2 a0 = make_float2(0.f, 0.f), a1 = a0, a2 = a0, a3 = a0;
  int i = s;
  for (; i + 3 < e; i += 4) {
    const int2 e0 = ep[i], e1 = ep[i + 1], e2 = ep[i + 2], e3 = ep[i + 3];
    const float2 g0 = __half22float2(*reinterpret_cast<const __half2*>(h + (size_t)e0.x * hstride + c2));
    const float2 g1 = __half22float2(*reinterpret_cast<const __half2*>(h + (size_t)e1.x * hstride + c2));
    const float2 g2 = __half22float2(*reinterpret_cast<const __half2*>(h + (size_t)e2.x * hstride + c2));
    const float2 g3 = __half22float2(*reinterpret_cast<const __half2*>(h + (size_t)e3.x * hstride + c2));
    const float v0 = __int_as_float(e0.y), v1 = __int_as_float(e1.y);
    const float v2 = __int_as_float(e2.y), v3 = __int_as_float(e3.y);
    a0.x += v0 * g0.x; a0.y += v0 * g0.y;
    a1.x += v1 * g1.x; a1.y += v1 * g1.y;
    a2.x += v2 * g2.x; a2.y += v2 * g2.y;
    a3.x += v3 * g3.x; a3.y += v3 * g3.y;
  }
  for (; i < e; ++i) {
    const int2 e0 = ep[i];
    const float v0 = __int_as_float(e0.y);
    const float2 g0 = __half22float2(*reinterpret_cast<const __half2*>(h + (size_t)e0.x * hstride + c2));
    a0.x += v0 * g0.x; a0.y += v0 * g0.y;
  }
  float2 res = make_float2((a0.x + a1.x) + (a2.x + a3.x),
                           (a0.y + a1.y) + (a2.y + a3.y));
  *reinterpret_cast<float2*>(outp + (size_t)r * ostride + c2) = res;
}

// ---- SpMM: fp16 gather -> fp16 table (fallback path) ------------------
__global__ __launch_bounds__(256) void spmm_h2h(
    const __half* __restrict__ h, int hstride, const int* __restrict__ rp,
    const int2* __restrict__ ep, __half* __restrict__ outp, int ostride, int N) {
  const int r = blockIdx.x * 4 + (threadIdx.x >> 6);
  if (r >= N) return;
  const int c2 = (threadIdx.x & 63) << 1;
  const int s = rp[r], e = rp[r + 1];
  float2 a0 = make_float2(0.f, 0.f), a1 = a0;
  int i = s;
  for (; i + 1 < e; i += 2) {
    const int2 e0 = ep[i], e1 = ep[i + 1];
    const float2 g0 = __half22float2(*reinterpret_cast<const __half2*>(h + (size_t)e0.x * hstride + c2));
    const float2 g1 = __half22float2(*reinterpret_cast<const __half2*>(h + (size_t)e1.x * hstride + c2));
    const float v0 = __int_as_float(e0.y), v1 = __int_as_float(e1.y);
    a0.x += v0 * g0.x; a0.y += v0 * g0.y;
    a1.x += v1 * g1.x; a1.y += v1 * g1.y;
  }
  if (i < e) {
    const int2 e0 = ep[i];
    const float v0 = __int_as_float(e0.y);
    const float2 g0 = __half22float2(*reinterpret_cast<const __half2*>(h + (size_t)e0.x * hstride + c2));
    a0.x += v0 * g0.x; a0.y += v0 * g0.y;
  }
  float2 res = make_float2(a0.x + a1.x, a0.y + a1.y);
  *reinterpret_cast<__half2*>(outp + (size_t)r * ostride + c2) = __float22half2_rn(res);
}

extern "C" void kernel_launch(void* const* d_in, const int* in_sizes, int n_in,
                              void* d_out, int out_size, void* d_ws, size_t ws_size,
                              hipStream_t stream) {
  const float* x  = (const float*)d_in[0];
  const float* W  = (const float*)d_in[1];
  const float* b  = (const float*)d_in[2];
  const float* ev = (const float*)d_in[3];
  const int*   er = (const int*)d_in[4];
  const int*   ec = (const int*)d_in[5];
  const int N = in_sizes[0] / C;
  const int E = in_sizes[3];
  float* out = (float*)d_out;

  // rows padded to 4096 (512 rows/chunk x 8 chunks per XCD-group)
  const int NP3 = ((N + 4095) / 4096) * 4096;
  const int nchunk = NP3 / 512;

  char* base = (char*)d_ws;
  size_t off = 0;
  auto alloc = [&](size_t bytes) {
    char* p = base + off;
    off += (bytes + 255) & ~(size_t)255;
    return p;
  };
  __half* h12 = (__half*)alloc((size_t)N * 256 * 2);  // interleaved h1|h2
  unsigned short* xh = (unsigned short*)alloc((size_t)NP3 * C * 2);
  unsigned short* xl = (unsigned short*)alloc((size_t)NP3 * C * 2);
  unsigned short* wf = (unsigned short*)alloc((size_t)12 * 8192 * 2);
  int* row_ptr = (int*)alloc((size_t)(N + 1) * 4);
  int* cursor  = (int*)alloc((size_t)N * 4);
  int* bsum    = (int*)alloc(64 * 4);
  int* carry   = (int*)alloc(64 * 4);
  int2* ep     = (int2*)alloc((size_t)E * 8);
  const size_t need_t = off + (size_t)N * C * 2;
  __half* t;
  int tstride;
  bool merged;
  if (ws_size >= need_t) {
    t = (__half*)alloc((size_t)N * C * 2);
    tstride = C;
    merged = true;
  } else {
    t = h12;        // alias h1-slots (dead after pass-1), stride 256
    tstride = 256;
    merged = false;
  }

  const int nb = (N + 1023) / 1024;

  // prep (weights + split x)
  prep_w<<<192, 256, 0, stream>>>(W, wf);
  prep_x<<<(NP3 * C + 255) / 256, 256, 0, stream>>>(x, xh, xl, N, NP3);

  // CSR build (cursor doubles as count buffer)
  hipMemsetAsync(cursor, 0, (size_t)N * sizeof(int), stream);
  const int eb0 = (E + 255) / 256;
  const int eblocks = eb0 < 2048 ? eb0 : 2048;
  hist_rows<<<eblocks, 256, 0, stream>>>(er, cursor, E);
  scan_local<<<nb, 1024, 0, stream>>>(cursor, row_ptr, bsum, N);
  scan_carry<<<1, 64, 0, stream>>>(bsum, carry, row_ptr, nb, N);
  scan_apply<<<nb, 1024, 0, stream>>>(row_ptr, carry, cursor, N);
  scatter_edges<<<eblocks, 256, 0, stream>>>(er, ec, ev, cursor, ep, E);

  // fused linears (MFMA, W-stationary in VGPRs)
  gemm3_ws<<<6 * nchunk, 256, 0, stream>>>(xh, xl, wf, b, out, h12, N);

  // SpMM passes
  const int sblocks = (N + 3) / 4;
  if (merged) {
    spmm12<<<sblocks, 256, 0, stream>>>(h12, row_ptr, ep, out, t, tstride, N);
  } else {
    spmm_h2f<<<sblocks, 256, 0, stream>>>(h12, 256, row_ptr, ep, out + C, N, 3 * C);
    spmm_h2h<<<sblocks, 256, 0, stream>>>(h12 + 128, 256, row_ptr, ep, t, tstride, N);
  }
  spmm_h2f<<<sblocks, 256, 0, stream>>>(t, tstride, row_ptr, ep, out + 2 * C, N, 3 * C);
}

// Round 11
// 204.915 us; speedup vs baseline: 1.9273x; 1.0061x over previous
//
#include <hip/hip_runtime.h>
#include <hip/hip_fp16.h>
#include <cstddef>
#include <cstdint>

#define C 128

typedef short bf16x8 __attribute__((ext_vector_type(8)));
typedef float f32x4 __attribute__((ext_vector_type(4)));

__device__ __forceinline__ unsigned f2bf_hi(float f) {
  unsigned u = __float_as_uint(f);
  return (u + 0x7fffu + ((u >> 16) & 1u)) >> 16;
}

__device__ __forceinline__ float4 gather8B(const __half* p) {
  const uint2 u = *reinterpret_cast<const uint2*>(p);
  const __half2 a = *reinterpret_cast<const __half2*>(&u.x);
  const __half2 b = *reinterpret_cast<const __half2*>(&u.y);
  const float2 lo = __half22float2(a), hi = __half22float2(b);
  return make_float4(lo.x, lo.y, hi.x, hi.y);
}

__device__ __forceinline__ void fma4(float4& acc, float v, const float4& g) {
  acc.x += v * g.x; acc.y += v * g.y; acc.z += v * g.z; acc.w += v * g.w;
}

__device__ __forceinline__ void red4(float4& a) {
  a.x += __shfl_xor(a.x, 32);
  a.y += __shfl_xor(a.y, 32);
  a.z += __shfl_xor(a.z, 32);
  a.w += __shfl_xor(a.w, 32);
}

// ---- W prep: W[j][k][c] fp32 -> fragment-ordered bf16 hi/lo planes ----
// 12 planes (j*4 + half*2 + ch), each 8192 shorts (64 cols x 128 k).
// Within plane: off = kc*2048 + ct*512 + (g*16 + l15)*8 + i   (verified R8)
__global__ __launch_bounds__(256) void prep_w(
    const float* __restrict__ W, unsigned short* __restrict__ wf) {
  const int idx = blockIdx.x * 256 + threadIdx.x;  // 0..49151
  const int j = idx >> 14, k = (idx >> 7) & 127, c = idx & 127;
  const float v = W[idx];
  const unsigned hb = f2bf_hi(v);
  const unsigned lb = f2bf_hi(v - __uint_as_float(hb << 16));
  const int ch = c >> 6, cc = c & 63, ct = cc >> 4, l15 = cc & 15;
  const int kc = k >> 5, kk = k & 31, g = kk >> 3, i = kk & 7;
  const int off = kc * 2048 + ct * 512 + (g * 16 + l15) * 8 + i;
  wf[(size_t)(j * 4 + 0 + ch) * 8192 + off] = (unsigned short)hb;  // hi plane
  wf[(size_t)(j * 4 + 2 + ch) * 8192 + off] = (unsigned short)lb;  // lo plane
}

// ---- x prep: fp32 [N][128] -> bf16 hi/lo [NP][128] (zero-padded) ------
__global__ __launch_bounds__(256) void prep_x(
    const float* __restrict__ x, unsigned short* __restrict__ xh,
    unsigned short* __restrict__ xl, int N, int NP) {
  const int idx = blockIdx.x * 256 + threadIdx.x;
  if (idx >= NP * C) return;
  const float v = (idx < N * C) ? x[idx] : 0.0f;
  const unsigned hb = f2bf_hi(v);
  const unsigned lb = f2bf_hi(v - __uint_as_float(hb << 16));
  xh[idx] = (unsigned short)hb;
  xl[idx] = (unsigned short)lb;
}

// ---- fused 3x linear: W-stationary in VGPRs, stream x rows ------------
// bid -> (chunk, v): chunk = (bid%8) + 8*(bid/48), v = (bid%48)>>3 = j*2+ch.
// h1/h2 outputs interleaved into h12 [N][256]: j==1 at +0, j==2 at +128.
__global__ __launch_bounds__(256, 2) void gemm3_ws(
    const unsigned short* __restrict__ xh, const unsigned short* __restrict__ xl,
    const unsigned short* __restrict__ wf, const float* __restrict__ bias,
    float* __restrict__ out, __half* __restrict__ h12, int N) {
  const int bid = blockIdx.x;
  const int q48 = bid / 48, r48 = bid % 48;
  const int chunk = (r48 & 7) + 8 * q48;
  const int v = r48 >> 3;  // 0..5
  const int j = v >> 1, ch = v & 1;
  const int tid = threadIdx.x;
  const int lane = tid & 63, wid = tid >> 6;
  const int l15 = lane & 15, g = lane >> 4;

  // stationary B fragments (128 VGPRs)
  const unsigned short* ph = wf + (size_t)(j * 4 + 0 + ch) * 8192 + lane * 8;
  const unsigned short* pl = wf + (size_t)(j * 4 + 2 + ch) * 8192 + lane * 8;
  bf16x8 bh[4][4], bl[4][4];
#pragma unroll
  for (int kc = 0; kc < 4; ++kc)
#pragma unroll
    for (int ct = 0; ct < 4; ++ct) {
      bh[kc][ct] = *reinterpret_cast<const bf16x8*>(ph + kc * 2048 + ct * 512);
      bl[kc][ct] = *reinterpret_cast<const bf16x8*>(pl + kc * 2048 + ct * 512);
    }

  float bv[4];
#pragma unroll
  for (int ct = 0; ct < 4; ++ct) bv[ct] = bias[j * C + ch * 64 + ct * 16 + l15];

  const int t0 = chunk * 32 + wid;  // 16-row tile id, step 4 per wave

  bf16x8 a0h[4], a0l[4], a1h[4], a1l[4];

#define LOADA(AH, AL, T)                                                    \
  {                                                                         \
    const size_t ar = (size_t)((T)*16 + l15) * C + g * 8;                   \
    _Pragma("unroll") for (int kc = 0; kc < 4; ++kc) {                      \
      AH[kc] = *reinterpret_cast<const bf16x8*>(xh + ar + kc * 32);         \
      AL[kc] = *reinterpret_cast<const bf16x8*>(xl + ar + kc * 32);         \
    }                                                                       \
  }

#define COMPSTORE(AH, AL, T)                                                \
  {                                                                         \
    f32x4 acc[4];                                                           \
    _Pragma("unroll") for (int ct = 0; ct < 4; ++ct)                        \
        acc[ct] = (f32x4){0.f, 0.f, 0.f, 0.f};                              \
    _Pragma("unroll") for (int kc = 0; kc < 4; ++kc)                        \
        _Pragma("unroll") for (int ct = 0; ct < 4; ++ct) {                  \
      acc[ct] = __builtin_amdgcn_mfma_f32_16x16x32_bf16(AH[kc], bh[kc][ct], \
                                                        acc[ct], 0, 0, 0);  \
      acc[ct] = __builtin_amdgcn_mfma_f32_16x16x32_bf16(AL[kc], bh[kc][ct], \
                                                        acc[ct], 0, 0, 0);  \
      acc[ct] = __builtin_amdgcn_mfma_f32_16x16x32_bf16(AH[kc], bl[kc][ct], \
                                                        acc[ct], 0, 0, 0);  \
    }                                                                       \
    const int grb = (T)*16 + g * 4;                                         \
    if (j == 0) {                                                           \
      _Pragma("unroll") for (int ct = 0; ct < 4; ++ct) {                    \
        const int col = ch * 64 + ct * 16 + l15;                            \
        _Pragma("unroll") for (int qq = 0; qq < 4; ++qq) {                  \
          const int gr = grb + qq;                                          \
          if (gr < N) out[(size_t)gr * 384 + col] = acc[ct][qq] + bv[ct];   \
        }                                                                   \
      }                                                                     \
    } else {                                                                \
      __half* const hp = h12 + ((j == 2) ? 128 : 0);                        \
      _Pragma("unroll") for (int ct = 0; ct < 4; ++ct) {                    \
        const int col = ch * 64 + ct * 16 + l15;                            \
        _Pragma("unroll") for (int qq = 0; qq < 4; ++qq) {                  \
          const int gr = grb + qq;                                          \
          if (gr < N)                                                       \
            hp[(size_t)gr * 256 + col] = __float2half(acc[ct][qq] + bv[ct]);\
        }                                                                   \
      }                                                                     \
    }                                                                       \
  }

  LOADA(a0h, a0l, t0);
#pragma unroll
  for (int ti = 0; ti < 8; ti += 2) {
    LOADA(a1h, a1l, t0 + (ti + 1) * 4);
    COMPSTORE(a0h, a0l, t0 + ti * 4);
    if (ti + 2 < 8) LOADA(a0h, a0l, t0 + (ti + 2) * 4);
    COMPSTORE(a1h, a1l, t0 + (ti + 1) * 4);
  }
#undef LOADA
#undef COMPSTORE
}

// ---- CSR build --------------------------------------------------------
__global__ __launch_bounds__(256) void hist_rows(
    const int* __restrict__ row, int* __restrict__ cnt, int E) {
  int i = blockIdx.x * 256 + threadIdx.x;
  int stride = gridDim.x * 256;
  for (; i < E; i += stride) atomicAdd(&cnt[row[i]], 1);
}

__global__ __launch_bounds__(1024) void scan_local(
    const int* __restrict__ cnt, int* __restrict__ part,
    int* __restrict__ bsum, int N) {
  __shared__ int wsum[16];
  const int tid = threadIdx.x;
  const int i = blockIdx.x * 1024 + tid;
  const int v = (i < N) ? cnt[i] : 0;
  const int lane = tid & 63, w = tid >> 6;
  int s = v;
#pragma unroll
  for (int off = 1; off < 64; off <<= 1) {
    int t = __shfl_up(s, off, 64);
    if (lane >= off) s += t;
  }
  if (lane == 63) wsum[w] = s;
  __syncthreads();
  if (tid < 16) {
    int ws = wsum[tid];
#pragma unroll
    for (int off = 1; off < 16; off <<= 1) {
      int t = __shfl_up(ws, off, 16);
      if (tid >= off) ws += t;
    }
    wsum[tid] = ws;
  }
  __syncthreads();
  const int woff = w ? wsum[w - 1] : 0;
  if (i < N) part[i] = woff + s - v;
  if (tid == 0) bsum[blockIdx.x] = wsum[15];
}

__global__ __launch_bounds__(64) void scan_carry(
    const int* __restrict__ bsum, int* __restrict__ carry,
    int* __restrict__ row_ptr, int nb, int N) {
  const int tid = threadIdx.x;
  const int v = (tid < nb) ? bsum[tid] : 0;
  int s = v;
#pragma unroll
  for (int off = 1; off < 64; off <<= 1) {
    int t = __shfl_up(s, off, 64);
    if (tid >= off) s += t;
  }
  if (tid < nb) carry[tid] = s - v;
  if (tid == 63) row_ptr[N] = s;
}

__global__ __launch_bounds__(1024) void scan_apply(
    int* __restrict__ part, const int* __restrict__ carry,
    int* __restrict__ cursor, int N) {
  const int i = blockIdx.x * 1024 + threadIdx.x;
  if (i < N) {
    const int v = part[i] + carry[blockIdx.x];
    part[i] = v;
    cursor[i] = v;
  }
}

__global__ __launch_bounds__(256) void scatter_edges(
    const int* __restrict__ row, const int* __restrict__ col,
    const float* __restrict__ val, int* __restrict__ cursor,
    int2* __restrict__ ep, int E) {
  int i = blockIdx.x * 256 + threadIdx.x;
  int stride = gridDim.x * 256;
  for (; i < E; i += stride) {
    int r = row[i];
    int pos = atomicAdd(&cursor[r], 1);
    ep[pos] = make_int2(col[i], __float_as_int(val[i]));
  }
}

// ---- SpMM merged: out[:,128:256] = A h1 ; t = A h2 --------------------
// One row per wave; 2 edges in flight per iter (one per 32-lane half);
// each lane: 4 channels via 8B half4 gathers. Cross-half shfl_xor reduce.
__global__ __launch_bounds__(256) void spmm12(
    const __half* __restrict__ h12, const int* __restrict__ rp,
    const int2* __restrict__ ep, float* __restrict__ out,
    __half* __restrict__ t, int tstride, int N) {
  const int r = blockIdx.x * 4 + (threadIdx.x >> 6);
  if (r >= N) return;
  const int lane = threadIdx.x & 63;
  const int half = lane >> 5;
  const int c4 = (lane & 31) << 2;  // 4-channel base
  const int s = rp[r], e = rp[r + 1];
  float4 p0 = make_float4(0.f, 0.f, 0.f, 0.f), p1 = p0, q0 = p0, q1 = p0;
  int i = s + half;  // this half's edge stream: s+half, s+half+2, ...
  for (; i + 2 < e; i += 4) {
    const int2 e0 = ep[i], e1 = ep[i + 2];
    const float v0 = __int_as_float(e0.y), v1 = __int_as_float(e1.y);
    const __half* b0 = h12 + (size_t)e0.x * 256 + c4;
    const __half* b1 = h12 + (size_t)e1.x * 256 + c4;
    const float4 g0p = gather8B(b0);
    const float4 g0q = gather8B(b0 + 128);
    const float4 g1p = gather8B(b1);
    const float4 g1q = gather8B(b1 + 128);
    fma4(p0, v0, g0p); fma4(q0, v0, g0q);
    fma4(p1, v1, g1p); fma4(q1, v1, g1q);
  }
  if (i < e) {
    const int2 e0 = ep[i];
    const float v0 = __int_as_float(e0.y);
    const __half* b0 = h12 + (size_t)e0.x * 256 + c4;
    fma4(p0, v0, gather8B(b0));
    fma4(q0, v0, gather8B(b0 + 128));
  }
  p0.x += p1.x; p0.y += p1.y; p0.z += p1.z; p0.w += p1.w;
  q0.x += q1.x; q0.y += q1.y; q0.z += q1.z; q0.w += q1.w;
  red4(p0);
  red4(q0);
  if (half == 0) {
    *reinterpret_cast<float4*>(out + (size_t)r * 384 + C + c4) = p0;
  } else {
    const __half2 qa = __float22half2_rn(make_float2(q0.x, q0.y));
    const __half2 qb = __float22half2_rn(make_float2(q0.z, q0.w));
    uint2 st;
    st.x = *reinterpret_cast<const unsigned*>(&qa);
    st.y = *reinterpret_cast<const unsigned*>(&qb);
    *reinterpret_cast<uint2*>(t + (size_t)r * tstride + c4) = st;
  }
}

// ---- SpMM: fp16 gather (stride hstride) -> fp32 out slice -------------
// Same 2-edges-per-wave structure, single table.
__global__ __launch_bounds__(256) void spmm_h2f(
    const __half* __restrict__ h, int hstride, const int* __restrict__ rp,
    const int2* __restrict__ ep, float* __restrict__ outp, int N, int ostride) {
  const int r = blockIdx.x * 4 + (threadIdx.x >> 6);
  if (r >= N) return;
  const int lane = threadIdx.x & 63;
  const int half = lane >> 5;
  const int c4 = (lane & 31) << 2;
  const int s = rp[r], e = rp[r + 1];
  float4 a0 = make_float4(0.f, 0.f, 0.f, 0.f), a1 = a0;
  int i = s + half;
  for (; i + 2 < e; i += 4) {
    const int2 e0 = ep[i], e1 = ep[i + 2];
    const float v0 = __int_as_float(e0.y), v1 = __int_as_float(e1.y);
    const float4 g0 = gather8B(h + (size_t)e0.x * hstride + c4);
    const float4 g1 = gather8B(h + (size_t)e1.x * hstride + c4);
    fma4(a0, v0, g0);
    fma4(a1, v1, g1);
  }
  if (i < e) {
    const int2 e0 = ep[i];
    fma4(a0, __int_as_float(e0.y), gather8B(h + (size_t)e0.x * hstride + c4));
  }
  a0.x += a1.x; a0.y += a1.y; a0.z += a1.z; a0.w += a1.w;
  red4(a0);
  if (half == 0)
    *reinterpret_cast<float4*>(outp + (size_t)r * ostride + c4) = a0;
}

// ---- SpMM: fp16 gather -> fp16 table (fallback path only) -------------
__global__ __launch_bounds__(256) void spmm_h2h(
    const __half* __restrict__ h, int hstride, const int* __restrict__ rp,
    const int2* __restrict__ ep, __half* __restrict__ outp, int ostride, int N) {
  const int r = blockIdx.x * 4 + (threadIdx.x >> 6);
  if (r >= N) return;
  const int lane = threadIdx.x & 63;
  const int half = lane >> 5;
  const int c4 = (lane & 31) << 2;
  const int s = rp[r], e = rp[r + 1];
  float4 a0 = make_float4(0.f, 0.f, 0.f, 0.f), a1 = a0;
  int i = s + half;
  for (; i + 2 < e; i += 4) {
    const int2 e0 = ep[i], e1 = ep[i + 2];
    fma4(a0, __int_as_float(e0.y), gather8B(h + (size_t)e0.x * hstride + c4));
    fma4(a1, __int_as_float(e1.y), gather8B(h + (size_t)e1.x * hstride + c4));
  }
  if (i < e) {
    const int2 e0 = ep[i];
    fma4(a0, __int_as_float(e0.y), gather8B(h + (size_t)e0.x * hstride + c4));
  }
  a0.x += a1.x; a0.y += a1.y; a0.z += a1.z; a0.w += a1.w;
  red4(a0);
  if (half == 0) {
    const __half2 qa = __float22half2_rn(make_float2(a0.x, a0.y));
    const __half2 qb = __float22half2_rn(make_float2(a0.z, a0.w));
    uint2 st;
    st.x = *reinterpret_cast<const unsigned*>(&qa);
    st.y = *reinterpret_cast<const unsigned*>(&qb);
    *reinterpret_cast<uint2*>(outp + (size_t)r * ostride + c4) = st;
  }
}

extern "C" void kernel_launch(void* const* d_in, const int* in_sizes, int n_in,
                              void* d_out, int out_size, void* d_ws, size_t ws_size,
                              hipStream_t stream) {
  const float* x  = (const float*)d_in[0];
  const float* W  = (const float*)d_in[1];
  const float* b  = (const float*)d_in[2];
  const float* ev = (const float*)d_in[3];
  const int*   er = (const int*)d_in[4];
  const int*   ec = (const int*)d_in[5];
  const int N = in_sizes[0] / C;
  const int E = in_sizes[3];
  float* out = (float*)d_out;

  // rows padded to 4096 (512 rows/chunk x 8 chunks per XCD-group)
  const int NP3 = ((N + 4095) / 4096) * 4096;
  const int nchunk = NP3 / 512;

  char* base = (char*)d_ws;
  size_t off = 0;
  auto alloc = [&](size_t bytes) {
    char* p = base + off;
    off += (bytes + 255) & ~(size_t)255;
    return p;
  };
  __half* h12 = (__half*)alloc((size_t)N * 256 * 2);  // interleaved h1|h2
  unsigned short* xh = (unsigned short*)alloc((size_t)NP3 * C * 2);
  unsigned short* xl = (unsigned short*)alloc((size_t)NP3 * C * 2);
  unsigned short* wf = (unsigned short*)alloc((size_t)12 * 8192 * 2);
  int* row_ptr = (int*)alloc((size_t)(N + 1) * 4);
  int* cursor  = (int*)alloc((size_t)N * 4);
  int* bsum    = (int*)alloc(64 * 4);
  int* carry   = (int*)alloc(64 * 4);
  int2* ep     = (int2*)alloc((size_t)E * 8);
  const size_t need_t = off + (size_t)N * C * 2;
  __half* t;
  int tstride;
  bool merged;
  if (ws_size >= need_t) {
    t = (__half*)alloc((size_t)N * C * 2);
    tstride = C;
    merged = true;
  } else {
    t = h12;        // alias h1-slots (dead after pass-1), stride 256
    tstride = 256;
    merged = false;
  }

  const int nb = (N + 1023) / 1024;

  // prep (weights + split x)
  prep_w<<<192, 256, 0, stream>>>(W, wf);
  prep_x<<<(NP3 * C + 255) / 256, 256, 0, stream>>>(x, xh, xl, N, NP3);

  // CSR build (cursor doubles as count buffer)
  hipMemsetAsync(cursor, 0, (size_t)N * sizeof(int), stream);
  const int eb0 = (E + 255) / 256;
  const int eblocks = eb0 < 2048 ? eb0 : 2048;
  hist_rows<<<eblocks, 256, 0, stream>>>(er, cursor, E);
  scan_local<<<nb, 1024, 0, stream>>>(cursor, row_ptr, bsum, N);
  scan_carry<<<1, 64, 0, stream>>>(bsum, carry, row_ptr, nb, N);
  scan_apply<<<nb, 1024, 0, stream>>>(row_ptr, carry, cursor, N);
  scatter_edges<<<eblocks, 256, 0, stream>>>(er, ec, ev, cursor, ep, E);

  // fused linears (MFMA, W-stationary in VGPRs)
  gemm3_ws<<<6 * nchunk, 256, 0, stream>>>(xh, xl, wf, b, out, h12, N);

  // SpMM passes
  const int sblocks = (N + 3) / 4;
  if (merged) {
    spmm12<<<sblocks, 256, 0, stream>>>(h12, row_ptr, ep, out, t, tstride, N);
  } else {
    spmm_h2f<<<sblocks, 256, 0, stream>>>(h12, 256, row_ptr, ep, out + C, N, 3 * C);
    spmm_h2h<<<sblocks, 256, 0, stream>>>(h12 + 128, 256, row_ptr, ep, t, tstride, N);
  }
  spmm_h2f<<<sblocks, 256, 0, stream>>>(t, tstride, row_ptr, ep, out + 2 * C, N, 3 * C);
}

// Round 12
// 197.290 us; speedup vs baseline: 2.0018x; 1.0386x over previous
//
#include <hip/hip_runtime.h>
#include <hip/hip_fp16.h>
#include <cstddef>
#include <cstdint>

#define C 128

typedef short bf16x8 __attribute__((ext_vector_type(8)));
typedef float f32x4 __attribute__((ext_vector_type(4)));

__device__ __forceinline__ unsigned f2bf_hi(float f) {
  unsigned u = __float_as_uint(f);
  return (u + 0x7fffu + ((u >> 16) & 1u)) >> 16;
}

__device__ __forceinline__ float4 gather8B(const __half* p) {
  const uint2 u = *reinterpret_cast<const uint2*>(p);
  const __half2 a = *reinterpret_cast<const __half2*>(&u.x);
  const __half2 b = *reinterpret_cast<const __half2*>(&u.y);
  const float2 lo = __half22float2(a), hi = __half22float2(b);
  return make_float4(lo.x, lo.y, hi.x, hi.y);
}

__device__ __forceinline__ void fma4(float4& acc, float v, const float4& g) {
  acc.x += v * g.x; acc.y += v * g.y; acc.z += v * g.z; acc.w += v * g.w;
}

__device__ __forceinline__ void red4(float4& a) {
  a.x += __shfl_xor(a.x, 32);
  a.y += __shfl_xor(a.y, 32);
  a.z += __shfl_xor(a.z, 32);
  a.w += __shfl_xor(a.w, 32);
}

// ---- fused prep: W planes + x hi/lo split + cursor zeroing ------------
// W layout (verified R8): 12 planes (j*4 + half*2 + ch), 8192 shorts each;
// off = kc*2048 + ct*512 + (g*16+l15)*8 + i.
__global__ __launch_bounds__(256) void prep_fused(
    const float* __restrict__ W, unsigned short* __restrict__ wf,
    const float* __restrict__ x, unsigned short* __restrict__ xh,
    unsigned short* __restrict__ xl, int* __restrict__ cursor,
    int N, int NP) {
  const int idx = blockIdx.x * 256 + threadIdx.x;
  if (idx < NP * C) {
    const float v = (idx < N * C) ? x[idx] : 0.0f;
    const unsigned hb = f2bf_hi(v);
    const unsigned lb = f2bf_hi(v - __uint_as_float(hb << 16));
    xh[idx] = (unsigned short)hb;
    xl[idx] = (unsigned short)lb;
  }
  if (idx < 3 * 128 * 128) {
    const int j = idx >> 14, k = (idx >> 7) & 127, c = idx & 127;
    const float v = W[idx];
    const unsigned hb = f2bf_hi(v);
    const unsigned lb = f2bf_hi(v - __uint_as_float(hb << 16));
    const int ch = c >> 6, cc = c & 63, ct = cc >> 4, l15 = cc & 15;
    const int kc = k >> 5, kk = k & 31, g = kk >> 3, i = kk & 7;
    const int off = kc * 2048 + ct * 512 + (g * 16 + l15) * 8 + i;
    wf[(size_t)(j * 4 + 0 + ch) * 8192 + off] = (unsigned short)hb;
    wf[(size_t)(j * 4 + 2 + ch) * 8192 + off] = (unsigned short)lb;
  }
  if (idx < N) cursor[idx] = 0;
}

// ---- fused 3x linear: W-stationary in VGPRs, stream x rows ------------
// bid -> (chunk, v): chunk = (bid%8) + 8*(bid/48), v = (bid%48)>>3 = j*2+ch.
// h1/h2 interleaved into h12 [N][256]: j==1 at +0, j==2 at +128.
__global__ __launch_bounds__(256, 2) void gemm3_ws(
    const unsigned short* __restrict__ xh, const unsigned short* __restrict__ xl,
    const unsigned short* __restrict__ wf, const float* __restrict__ bias,
    float* __restrict__ out, __half* __restrict__ h12, int N) {
  const int bid = blockIdx.x;
  const int q48 = bid / 48, r48 = bid % 48;
  const int chunk = (r48 & 7) + 8 * q48;
  const int v = r48 >> 3;  // 0..5
  const int j = v >> 1, ch = v & 1;
  const int tid = threadIdx.x;
  const int lane = tid & 63, wid = tid >> 6;
  const int l15 = lane & 15, g = lane >> 4;

  // stationary B fragments (128 VGPRs)
  const unsigned short* ph = wf + (size_t)(j * 4 + 0 + ch) * 8192 + lane * 8;
  const unsigned short* pl = wf + (size_t)(j * 4 + 2 + ch) * 8192 + lane * 8;
  bf16x8 bh[4][4], bl[4][4];
#pragma unroll
  for (int kc = 0; kc < 4; ++kc)
#pragma unroll
    for (int ct = 0; ct < 4; ++ct) {
      bh[kc][ct] = *reinterpret_cast<const bf16x8*>(ph + kc * 2048 + ct * 512);
      bl[kc][ct] = *reinterpret_cast<const bf16x8*>(pl + kc * 2048 + ct * 512);
    }

  float bv[4];
#pragma unroll
  for (int ct = 0; ct < 4; ++ct) bv[ct] = bias[j * C + ch * 64 + ct * 16 + l15];

  const int t0 = chunk * 32 + wid;  // 16-row tile id, step 4 per wave

  bf16x8 a0h[4], a0l[4], a1h[4], a1l[4];

#define LOADA(AH, AL, T)                                                    \
  {                                                                         \
    const size_t ar = (size_t)((T)*16 + l15) * C + g * 8;                   \
    _Pragma("unroll") for (int kc = 0; kc < 4; ++kc) {                      \
      AH[kc] = *reinterpret_cast<const bf16x8*>(xh + ar + kc * 32);         \
      AL[kc] = *reinterpret_cast<const bf16x8*>(xl + ar + kc * 32);         \
    }                                                                       \
  }

#define COMPSTORE(AH, AL, T)                                                \
  {                                                                         \
    f32x4 acc[4];                                                           \
    _Pragma("unroll") for (int ct = 0; ct < 4; ++ct)                        \
        acc[ct] = (f32x4){0.f, 0.f, 0.f, 0.f};                              \
    _Pragma("unroll") for (int kc = 0; kc < 4; ++kc)                        \
        _Pragma("unroll") for (int ct = 0; ct < 4; ++ct) {                  \
      acc[ct] = __builtin_amdgcn_mfma_f32_16x16x32_bf16(AH[kc], bh[kc][ct], \
                                                        acc[ct], 0, 0, 0);  \
      acc[ct] = __builtin_amdgcn_mfma_f32_16x16x32_bf16(AL[kc], bh[kc][ct], \
                                                        acc[ct], 0, 0, 0);  \
      acc[ct] = __builtin_amdgcn_mfma_f32_16x16x32_bf16(AH[kc], bl[kc][ct], \
                                                        acc[ct], 0, 0, 0);  \
    }                                                                       \
    const int grb = (T)*16 + g * 4;                                         \
    if (j == 0) {                                                           \
      _Pragma("unroll") for (int ct = 0; ct < 4; ++ct) {                    \
        const int col = ch * 64 + ct * 16 + l15;                            \
        _Pragma("unroll") for (int qq = 0; qq < 4; ++qq) {                  \
          const int gr = grb + qq;                                          \
          if (gr < N) out[(size_t)gr * 384 + col] = acc[ct][qq] + bv[ct];   \
        }                                                                   \
      }                                                                     \
    } else {                                                                \
      __half* const hp = h12 + ((j == 2) ? 128 : 0);                        \
      _Pragma("unroll") for (int ct = 0; ct < 4; ++ct) {                    \
        const int colb = ch * 64 + ct * 16 + (l15 & ~1);                    \
        _Pragma("unroll") for (int qq = 0; qq < 4; ++qq) {                  \
          const int gr = grb + qq;                                          \
          const float fv = acc[ct][qq] + bv[ct];                            \
          const unsigned mine = (unsigned)__half_as_ushort(__float2half(fv));\
          const unsigned nbr = (unsigned)__shfl_xor((int)mine, 1);          \
          if (((l15 & 1) == 0) && gr < N) {                                 \
            *reinterpret_cast<unsigned*>(hp + (size_t)gr * 256 + colb) =    \
                mine | (nbr << 16);                                         \
          }                                                                 \
        }                                                                   \
      }                                                                     \
    }                                                                       \
  }

  LOADA(a0h, a0l, t0);
#pragma unroll
  for (int ti = 0; ti < 8; ti += 2) {
    LOADA(a1h, a1l, t0 + (ti + 1) * 4);
    COMPSTORE(a0h, a0l, t0 + ti * 4);
    if (ti + 2 < 8) LOADA(a0h, a0l, t0 + (ti + 2) * 4);
    COMPSTORE(a1h, a1l, t0 + (ti + 1) * 4);
  }
#undef LOADA
#undef COMPSTORE
}

// ---- CSR build --------------------------------------------------------
__global__ __launch_bounds__(256) void hist_rows(
    const int* __restrict__ row, int* __restrict__ cnt, int E) {
  int i = blockIdx.x * 256 + threadIdx.x;
  int stride = gridDim.x * 256;
  for (; i < E; i += stride) atomicAdd(&cnt[row[i]], 1);
}

__global__ __launch_bounds__(1024) void scan_local(
    const int* __restrict__ cnt, int* __restrict__ part,
    int* __restrict__ bsum, int N) {
  __shared__ int wsum[16];
  const int tid = threadIdx.x;
  const int i = blockIdx.x * 1024 + tid;
  const int v = (i < N) ? cnt[i] : 0;
  const int lane = tid & 63, w = tid >> 6;
  int s = v;
#pragma unroll
  for (int off = 1; off < 64; off <<= 1) {
    int t = __shfl_up(s, off, 64);
    if (lane >= off) s += t;
  }
  if (lane == 63) wsum[w] = s;
  __syncthreads();
  if (tid < 16) {
    int ws = wsum[tid];
#pragma unroll
    for (int off = 1; off < 16; off <<= 1) {
      int t = __shfl_up(ws, off, 16);
      if (tid >= off) ws += t;
    }
    wsum[tid] = ws;
  }
  __syncthreads();
  const int woff = w ? wsum[w - 1] : 0;
  if (i < N) part[i] = woff + s - v;
  if (tid == 0) bsum[blockIdx.x] = wsum[15];
}

// apply: part[i] += carry(bid); cursor = part; block0 writes row_ptr[N].
// carry recomputed per block from bsum via 64-lane prefix (nb <= 64).
__global__ __launch_bounds__(1024) void scan_apply2(
    int* __restrict__ part, const int* __restrict__ bsum,
    int* __restrict__ cursor, int* __restrict__ row_ptr, int nb, int N) {
  __shared__ int carry_s;
  const int tid = threadIdx.x;
  if (tid < 64) {
    const int v = (tid < nb) ? bsum[tid] : 0;
    int s = v;
#pragma unroll
    for (int off = 1; off < 64; off <<= 1) {
      int t = __shfl_up(s, off, 64);
      if (tid >= off) s += t;
    }
    if (tid == (int)blockIdx.x) carry_s = s - v;     // exclusive prefix @ bid
    if (blockIdx.x == 0 && tid == 63) row_ptr[N] = s;  // grand total
  }
  __syncthreads();
  const int i = blockIdx.x * 1024 + tid;
  if (i < N) {
    const int v = part[i] + carry_s;
    part[i] = v;
    cursor[i] = v;
  }
}

__global__ __launch_bounds__(256) void scatter_edges(
    const int* __restrict__ row, const int* __restrict__ col,
    const float* __restrict__ val, int* __restrict__ cursor,
    int2* __restrict__ ep, int E) {
  int i = blockIdx.x * 256 + threadIdx.x;
  int stride = gridDim.x * 256;
  for (; i < E; i += stride) {
    int r = row[i];
    int pos = atomicAdd(&cursor[r], 1);
    ep[pos] = make_int2(col[i], __float_as_int(val[i]));
  }
}

// ---- SpMM merged: out[:,128:256] = A h1 ; t = A h2 --------------------
// One row per wave; 2 edges in flight (one per 32-lane half); 8B gathers.
__global__ __launch_bounds__(256) void spmm12(
    const __half* __restrict__ h12, const int* __restrict__ rp,
    const int2* __restrict__ ep, float* __restrict__ out,
    __half* __restrict__ t, int tstride, int N) {
  const int r = blockIdx.x * 4 + (threadIdx.x >> 6);
  if (r >= N) return;
  const int lane = threadIdx.x & 63;
  const int half = lane >> 5;
  const int c4 = (lane & 31) << 2;
  const int s = rp[r], e = rp[r + 1];
  float4 p0 = make_float4(0.f, 0.f, 0.f, 0.f), p1 = p0, q0 = p0, q1 = p0;
  int i = s + half;
  for (; i + 2 < e; i += 4) {
    const int2 e0 = ep[i], e1 = ep[i + 2];
    const float v0 = __int_as_float(e0.y), v1 = __int_as_float(e1.y);
    const __half* b0 = h12 + (size_t)e0.x * 256 + c4;
    const __half* b1 = h12 + (size_t)e1.x * 256 + c4;
    const float4 g0p = gather8B(b0);
    const float4 g0q = gather8B(b0 + 128);
    const float4 g1p = gather8B(b1);
    const float4 g1q = gather8B(b1 + 128);
    fma4(p0, v0, g0p); fma4(q0, v0, g0q);
    fma4(p1, v1, g1p); fma4(q1, v1, g1q);
  }
  if (i < e) {
    const int2 e0 = ep[i];
    const float v0 = __int_as_float(e0.y);
    const __half* b0 = h12 + (size_t)e0.x * 256 + c4;
    fma4(p0, v0, gather8B(b0));
    fma4(q0, v0, gather8B(b0 + 128));
  }
  p0.x += p1.x; p0.y += p1.y; p0.z += p1.z; p0.w += p1.w;
  q0.x += q1.x; q0.y += q1.y; q0.z += q1.z; q0.w += q1.w;
  red4(p0);
  red4(q0);
  if (half == 0) {
    *reinterpret_cast<float4*>(out + (size_t)r * 384 + C + c4) = p0;
  } else {
    const __half2 qa = __float22half2_rn(make_float2(q0.x, q0.y));
    const __half2 qb = __float22half2_rn(make_float2(q0.z, q0.w));
    uint2 st;
    st.x = *reinterpret_cast<const unsigned*>(&qa);
    st.y = *reinterpret_cast<const unsigned*>(&qb);
    *reinterpret_cast<uint2*>(t + (size_t)r * tstride + c4) = st;
  }
}

// ---- SpMM: fp16 gather (stride hstride) -> fp32 out slice -------------
__global__ __launch_bounds__(256) void spmm_h2f(
    const __half* __restrict__ h, int hstride, const int* __restrict__ rp,
    const int2* __restrict__ ep, float* __restrict__ outp, int N, int ostride) {
  const int r = blockIdx.x * 4 + (threadIdx.x >> 6);
  if (r >= N) return;
  const int lane = threadIdx.x & 63;
  const int half = lane >> 5;
  const int c4 = (lane & 31) << 2;
  const int s = rp[r], e = rp[r + 1];
  float4 a0 = make_float4(0.f, 0.f, 0.f, 0.f), a1 = a0;
  int i = s + half;
  for (; i + 2 < e; i += 4) {
    const int2 e0 = ep[i], e1 = ep[i + 2];
    const float v0 = __int_as_float(e0.y), v1 = __int_as_float(e1.y);
    const float4 g0 = gather8B(h + (size_t)e0.x * hstride + c4);
    const float4 g1 = gather8B(h + (size_t)e1.x * hstride + c4);
    fma4(a0, v0, g0);
    fma4(a1, v1, g1);
  }
  if (i < e) {
    const int2 e0 = ep[i];
    fma4(a0, __int_as_float(e0.y), gather8B(h + (size_t)e0.x * hstride + c4));
  }
  a0.x += a1.x; a0.y += a1.y; a0.z += a1.z; a0.w += a1.w;
  red4(a0);
  if (half == 0)
    *reinterpret_cast<float4*>(outp + (size_t)r * ostride + c4) = a0;
}

// ---- SpMM: fp16 gather -> fp16 table (fallback path only) -------------
__global__ __launch_bounds__(256) void spmm_h2h(
    const __half* __restrict__ h, int hstride, const int* __restrict__ rp,
    const int2* __restrict__ ep, __half* __restrict__ outp, int ostride, int N) {
  const int r = blockIdx.x * 4 + (threadIdx.x >> 6);
  if (r >= N) return;
  const int lane = threadIdx.x & 63;
  const int half = lane >> 5;
  const int c4 = (lane & 31) << 2;
  const int s = rp[r], e = rp[r + 1];
  float4 a0 = make_float4(0.f, 0.f, 0.f, 0.f), a1 = a0;
  int i = s + half;
  for (; i + 2 < e; i += 4) {
    const int2 e0 = ep[i], e1 = ep[i + 2];
    fma4(a0, __int_as_float(e0.y), gather8B(h + (size_t)e0.x * hstride + c4));
    fma4(a1, __int_as_float(e1.y), gather8B(h + (size_t)e1.x * hstride + c4));
  }
  if (i < e) {
    const int2 e0 = ep[i];
    fma4(a0, __int_as_float(e0.y), gather8B(h + (size_t)e0.x * hstride + c4));
  }
  a0.x += a1.x; a0.y += a1.y; a0.z += a1.z; a0.w += a1.w;
  red4(a0);
  if (half == 0) {
    const __half2 qa = __float22half2_rn(make_float2(a0.x, a0.y));
    const __half2 qb = __float22half2_rn(make_float2(a0.z, a0.w));
    uint2 st;
    st.x = *reinterpret_cast<const unsigned*>(&qa);
    st.y = *reinterpret_cast<const unsigned*>(&qb);
    *reinterpret_cast<uint2*>(outp + (size_t)r * ostride + c4) = st;
  }
}

extern "C" void kernel_launch(void* const* d_in, const int* in_sizes, int n_in,
                              void* d_out, int out_size, void* d_ws, size_t ws_size,
                              hipStream_t stream) {
  const float* x  = (const float*)d_in[0];
  const float* W  = (const float*)d_in[1];
  const float* b  = (const float*)d_in[2];
  const float* ev = (const float*)d_in[3];
  const int*   er = (const int*)d_in[4];
  const int*   ec = (const int*)d_in[5];
  const int N = in_sizes[0] / C;
  const int E = in_sizes[3];
  float* out = (float*)d_out;

  // rows padded to 4096 (512 rows/chunk x 8 chunks per XCD-group)
  const int NP3 = ((N + 4095) / 4096) * 4096;
  const int nchunk = NP3 / 512;

  char* base = (char*)d_ws;
  size_t off = 0;
  auto alloc = [&](size_t bytes) {
    char* p = base + off;
    off += (bytes + 255) & ~(size_t)255;
    return p;
  };
  __half* h12 = (__half*)alloc((size_t)N * 256 * 2);  // interleaved h1|h2
  unsigned short* xh = (unsigned short*)alloc((size_t)NP3 * C * 2);
  unsigned short* xl = (unsigned short*)alloc((size_t)NP3 * C * 2);
  unsigned short* wf = (unsigned short*)alloc((size_t)12 * 8192 * 2);
  int* row_ptr = (int*)alloc((size_t)(N + 1) * 4);
  int* cursor  = (int*)alloc((size_t)N * 4);
  int* bsum    = (int*)alloc(64 * 4);
  int2* ep     = (int2*)alloc((size_t)E * 8);
  const size_t need_t = off + (size_t)N * C * 2;
  __half* t;
  int tstride;
  bool merged;
  if (ws_size >= need_t) {
    t = (__half*)alloc((size_t)N * C * 2);
    tstride = C;
    merged = true;
  } else {
    t = h12;        // alias h1-slots (dead after pass-1), stride 256
    tstride = 256;
    merged = false;
  }

  const int nb = (N + 1023) / 1024;

  // fused prep: W planes + x split + cursor zeroing (one dispatch)
  prep_fused<<<(NP3 * C + 255) / 256, 256, 0, stream>>>(W, wf, x, xh, xl,
                                                        cursor, N, NP3);

  // CSR build
  const int eb0 = (E + 255) / 256;
  const int eblocks = eb0 < 2048 ? eb0 : 2048;
  hist_rows<<<eblocks, 256, 0, stream>>>(er, cursor, E);
  scan_local<<<nb, 1024, 0, stream>>>(cursor, row_ptr, bsum, N);
  scan_apply2<<<nb, 1024, 0, stream>>>(row_ptr, bsum, cursor, row_ptr, nb, N);
  scatter_edges<<<eblocks, 256, 0, stream>>>(er, ec, ev, cursor, ep, E);

  // fused linears (MFMA, W-stationary in VGPRs)
  gemm3_ws<<<6 * nchunk, 256, 0, stream>>>(xh, xl, wf, b, out, h12, N);

  // SpMM passes
  const int sblocks = (N + 3) / 4;
  if (merged) {
    spmm12<<<sblocks, 256, 0, stream>>>(h12, row_ptr, ep, out, t, tstride, N);
  } else {
    spmm_h2f<<<sblocks, 256, 0, stream>>>(h12, 256, row_ptr, ep, out + C, N, 3 * C);
    spmm_h2h<<<sblocks, 256, 0, stream>>>(h12 + 128, 256, row_ptr, ep, t, tstride, N);
  }
  spmm_h2f<<<sblocks, 256, 0, stream>>>(t, tstride, row_ptr, ep, out + 2 * C, N, 3 * C);
}